// Round 1
// baseline (37224.893 us; speedup 1.0000x reference)
//
#include <hip/hip_runtime.h>
#include <math.h>

#define HDIM 1024
#define NWG 128
#define TPB 256
#define KCHK 16

struct RecArgs {
  const float* whh_l; const float* whh_r;
  const float* glc; const float* glf; const float* grc; const float* grf;
  float* hbuf;        // [2][HDIM]
  float* hsl;         // [n][HDIM]
  float* hsr;         // [n][HDIM]
  int* flags;         // [NWG]
  int* convf;         // [ncp][NWG], write-once per slot
  const int* pstart; const int* pend;
  int n;
};

// ---------------- setup: target vector, special rows, zero state ----------------
__global__ void setup_kernel(const int* __restrict__ x, const int* ts, const int* te,
                             const float* __restrict__ emb,
                             float* target, float* seqfl, float* seqfr,
                             float* hbuf, int* flags, int n) {
  int e = threadIdx.x;  // 0..1023
  int start = ts[0], end = te[0];
  int first_l = (start > 0) ? 0 : (end + 1);
  int first_r = (end < n - 1) ? (n - 1) : (start - 1);
  int fl = min(max(first_l, 0), n - 1);
  int fr = min(max(first_r, 0), n - 1);
  float sum = 0.f;
  for (int p = start; p <= end; ++p) sum += emb[(size_t)x[p] * HDIM + e];
  target[e] = sum / (float)(end - start + 1);
  seqfl[e] = emb[(size_t)x[fl] * HDIM + e];
  seqfr[e] = emb[(size_t)x[fr] * HDIM + e];
  hbuf[e] = 0.f;
  hbuf[HDIM + e] = 0.f;
  if (e < NWG) flags[e] = 0;
}

// ---------------- gate-constant vectors: w_ih@v + b_ih + b_hh ----------------
__global__ __launch_bounds__(256) void gateconst_kernel(
    const float* __restrict__ wih_l, const float* bih_l, const float* bhh_l,
    const float* __restrict__ wih_r, const float* bih_r, const float* bhh_r,
    const float* __restrict__ target, const float* __restrict__ seqfl,
    const float* __restrict__ seqfr,
    float* glc, float* glf, float* grc, float* grf) {
  int side = blockIdx.y;
  const float* wih = side ? wih_r : wih_l;
  const float* bih = side ? bih_r : bih_l;
  const float* bhh = side ? bhh_r : bhh_l;
  const float* sf = side ? seqfr : seqfl;
  float* outc = side ? grc : glc;
  float* outf = side ? grf : glf;
  int wv = threadIdx.x >> 6, lane = threadIdx.x & 63;
  int r = blockIdx.x * 4 + wv;  // 0..4095
  const float4* wrow = (const float4*)(wih + (size_t)r * HDIM);
  const float4* tg4 = (const float4*)target;
  const float4* sf4 = (const float4*)sf;
  float dc = 0.f, df = 0.f;
#pragma unroll
  for (int k = 0; k < 4; ++k) {
    float4 w4 = wrow[lane + 64 * k];
    float4 t4 = tg4[lane + 64 * k];
    float4 s4 = sf4[lane + 64 * k];
    dc += w4.x * t4.x + w4.y * t4.y + w4.z * t4.z + w4.w * t4.w;
    df += w4.x * s4.x + w4.y * s4.y + w4.z * s4.z + w4.w * s4.w;
  }
  for (int off = 32; off; off >>= 1) {
    dc += __shfl_xor(dc, off);
    df += __shfl_xor(df, off);
  }
  if (lane == 0) {
    float bb = bih[r] + bhh[r];
    outc[r] = dc + bb;
    outf[r] = df + bb;
  }
}

// ---------------- persistent cooperative recurrence ----------------
__global__ __launch_bounds__(TPB, 1) void rec_kernel(RecArgs a) {
  const int w = blockIdx.x;
  const int tid = threadIdx.x;
  const int lane = tid & 63;
  const int wave = tid >> 6;
  const int half = lane >> 5;
  const int rloc = lane & 31;          // local row 0..31
  const int cb = wave * 2 + half;      // column block 0..7
  const int gate = rloc >> 3;          // 0..3 (i,f,g,o)
  const int j = rloc & 7;              // local h index 0..7
  const int col0 = cb * 128;
  const int R = gate * HDIM + w * 8 + j;  // global gate row
  const int n = a.n;

  __shared__ float lds_part[8][32];
  __shared__ float lds_gates[32];
  __shared__ float lds_h8[8];
  __shared__ int lds_ctrl;

  const int start = a.pstart[0];
  const int end = a.pend[0];
  const int first_l = (start > 0) ? 0 : (end + 1);
  const int first_r = (end < n - 1) ? (n - 1) : (start - 1);

  float4 wreg[32];
  float cstate = 0.f, hprev = 0.f;  // lanes 0..7 of wave 0 own h/c state for col w*8+j

  for (int pass = 0; pass < 2; ++pass) {
    const float* whh = pass ? a.whh_r : a.whh_l;
    const float* gcv = pass ? a.grc : a.glc;
    const float* gfv = pass ? a.grf : a.glf;
    float* hsout = pass ? a.hsr : a.hsl;
    const int tspecial = pass ? (n - 1 - first_r) : first_l;
    const int sbase = pass * n;

    {  // load this pass's recurrent weights into registers
      const float4* wrow = (const float4*)(whh + (size_t)R * HDIM + col0);
#pragma unroll
      for (int k = 0; k < 32; ++k) wreg[k] = wrow[k];
    }
    float my_gc = 0.f, my_gf = 0.f;
    if (wave == 0 && lane < 32) { my_gc = gcv[R]; my_gf = gfv[R]; }

    bool fin = false;
    for (int t = 0; t < n && !fin; ++t) {
      const int s = sbase + t;
      int convdec = 0;
      if (wave == 0) {
        if (s > 0) {
          int guard = 0;
          for (;;) {
            int f1 = __hip_atomic_load(&a.flags[lane], __ATOMIC_ACQUIRE, __HIP_MEMORY_SCOPE_AGENT);
            int f2 = __hip_atomic_load(&a.flags[lane + 64], __ATOMIC_ACQUIRE, __HIP_MEMORY_SCOPE_AGENT);
            if (__all(f1 >= s && f2 >= s)) break;
            if (++guard > 50000000) break;  // anti-hang safety
          }
        }
        // consensus convergence decision at checkpoints (write-once convf slots)
        if (t > 0 && (t % KCHK) == 0 && (t - 1) > tspecial) {
          const int cp = s / KCHK - 1;
          int c1 = a.convf[(size_t)cp * NWG + lane];
          int c2 = a.convf[(size_t)cp * NWG + lane + 64];
          convdec = __all(c1 != 0 && c2 != 0);
        }
        if (lane == 0) lds_ctrl = convdec;
      }
      __syncthreads();
      convdec = lds_ctrl;

      if (convdec) {
        // bitwise fixed point: fill remaining hs rows with constant h, jump to pass end
        const int col = tid & 7;
        const float hv = lds_h8[col];
        for (int tt = t + (tid >> 3); tt < n; tt += 32)
          hsout[(size_t)tt * HDIM + w * 8 + col] = hv;
        if (wave == 0 && lane < 8)
          __hip_atomic_store(&a.hbuf[w * 8 + j], hprev, __ATOMIC_RELAXED, __HIP_MEMORY_SCOPE_AGENT);
        __syncthreads();
        if (tid == 0)
          __hip_atomic_store(&a.flags[w], sbase + n, __ATOMIC_RELEASE, __HIP_MEMORY_SCOPE_AGENT);
        fin = true;
        continue;
      }

      {  // partial dot: rows rloc, cols [col0, col0+128)
        const float4* h4 = (const float4*)(a.hbuf + (size_t)(s & 1) * HDIM + col0);
        float s0 = 0.f, s1 = 0.f, s2 = 0.f, s3 = 0.f;
#pragma unroll
        for (int k = 0; k < 32; k += 4) {
          float4 ha = h4[k + 0], hb = h4[k + 1], hc = h4[k + 2], hd = h4[k + 3];
          s0 += wreg[k + 0].x * ha.x + wreg[k + 0].y * ha.y + wreg[k + 0].z * ha.z + wreg[k + 0].w * ha.w;
          s1 += wreg[k + 1].x * hb.x + wreg[k + 1].y * hb.y + wreg[k + 1].z * hb.z + wreg[k + 1].w * hb.w;
          s2 += wreg[k + 2].x * hc.x + wreg[k + 2].y * hc.y + wreg[k + 2].z * hc.z + wreg[k + 2].w * hc.w;
          s3 += wreg[k + 3].x * hd.x + wreg[k + 3].y * hd.y + wreg[k + 3].z * hd.z + wreg[k + 3].w * hd.w;
        }
        lds_part[cb][rloc] = (s0 + s1) + (s2 + s3);
      }
      __syncthreads();
      if (wave == 0 && lane < 32) {
        float sum = 0.f;
#pragma unroll
        for (int b = 0; b < 8; ++b) sum += lds_part[b][rloc];
        sum += (t == tspecial) ? my_gf : my_gc;
        lds_gates[rloc] = sum;
      }
      __syncthreads();
      int mychanged = 0;
      if (wave == 0) {
        if (lane < 8) {
          float gi = lds_gates[j], gff = lds_gates[8 + j];
          float gg = lds_gates[16 + j], go = lds_gates[24 + j];
          float iv = 1.f / (1.f + expf(-gi));
          float fv = 1.f / (1.f + expf(-gff));
          float gv = tanhf(gg);
          float ov = 1.f / (1.f + expf(-go));
          float cnew = fv * cstate + iv * gv;
          float hn = ov * tanhf(cnew);
          mychanged = (__float_as_uint(hn) != __float_as_uint(hprev)) ||
                      (__float_as_uint(cnew) != __float_as_uint(cstate));
          cstate = cnew;
          hprev = hn;
          __hip_atomic_store(&a.hbuf[(size_t)((s + 1) & 1) * HDIM + w * 8 + j], hn,
                             __ATOMIC_RELAXED, __HIP_MEMORY_SCOPE_AGENT);
          hsout[(size_t)t * HDIM + w * 8 + j] = hn;
          lds_h8[j] = hn;
        }
        int anych = __any(mychanged);
        if (lane == 0 && ((t + 1) % KCHK) == 0) {
          const int cp = (s + 1) / KCHK - 1;
          __hip_atomic_store(&a.convf[(size_t)cp * NWG + w], anych ? 0 : 1,
                             __ATOMIC_RELAXED, __HIP_MEMORY_SCOPE_AGENT);
        }
      }
      __syncthreads();  // drains vmcnt: all h stores at LLC before flag release
      if (tid == 0)
        __hip_atomic_store(&a.flags[w], s + 1, __ATOMIC_RELEASE, __HIP_MEMORY_SCOPE_AGENT);
    }
  }
}

// ---------------- lin1_w transpose: L1T[k][j] = lin1_w[j][k] ----------------
__global__ void transpose_kernel(const float* __restrict__ A, float* __restrict__ AT) {
  __shared__ float tile[32][33];
  int j0 = blockIdx.y * 32, k0 = blockIdx.x * 32;
  int tx = threadIdx.x & 31, ty = threadIdx.x >> 5;  // ty 0..7
  for (int r = ty; r < 32; r += 8) tile[r][tx] = A[(size_t)(j0 + r) * HDIM + k0 + tx];
  __syncthreads();
  for (int r = ty; r < 32; r += 8) AT[(size_t)(k0 + r) * HDIM + j0 + tx] = tile[tx][r];
}

// ---------------- beta[t] = sum_j u[j]*tanh( (O @ L1^T)[t][j] + b1[j] ) ----------------
#define TT 8
__global__ __launch_bounds__(256) void beta_kernel(const float* __restrict__ hsl,
                                                   const float* __restrict__ hsr,
                                                   const float* __restrict__ L1T,
                                                   const float* __restrict__ b1,
                                                   const float* __restrict__ u,
                                                   float* __restrict__ beta) {
  __shared__ float OT[128][9];
  __shared__ float red[4][TT];
  const int t0 = blockIdx.x * TT;
  const int tid = threadIdx.x;
  float acc[4][TT] = {};
  const float4 uv = ((const float4*)u)[tid];
  const float4 bv = ((const float4*)b1)[tid];

  for (int k0 = 0; k0 < HDIM; k0 += 128) {
    {  // stage O tile transposed: OT[k][t] = hsl*hsr
      int tt = tid >> 5, kk = tid & 31;
      const float4* l4 = (const float4*)(hsl + (size_t)(t0 + tt) * HDIM + k0);
      const float4* r4 = (const float4*)(hsr + (size_t)(t0 + tt) * HDIM + k0);
      float4 aa = l4[kk], bb = r4[kk];
      OT[kk * 4 + 0][tt] = aa.x * bb.x;
      OT[kk * 4 + 1][tt] = aa.y * bb.y;
      OT[kk * 4 + 2][tt] = aa.z * bb.z;
      OT[kk * 4 + 3][tt] = aa.w * bb.w;
    }
    __syncthreads();
    const float4* lp = (const float4*)L1T + (size_t)k0 * (HDIM / 4);
    for (int k = 0; k < 128; ++k) {
      float4 lv = lp[(size_t)k * (HDIM / 4) + tid];
      float ov[TT];
#pragma unroll
      for (int t = 0; t < TT; ++t) ov[t] = OT[k][t];
#pragma unroll
      for (int t = 0; t < TT; ++t) {
        acc[0][t] += lv.x * ov[t];
        acc[1][t] += lv.y * ov[t];
        acc[2][t] += lv.z * ov[t];
        acc[3][t] += lv.w * ov[t];
      }
    }
    __syncthreads();
  }
  float lc[TT];
#pragma unroll
  for (int t = 0; t < TT; ++t)
    lc[t] = uv.x * tanhf(acc[0][t] + bv.x) + uv.y * tanhf(acc[1][t] + bv.y) +
            uv.z * tanhf(acc[2][t] + bv.z) + uv.w * tanhf(acc[3][t] + bv.w);
  for (int off = 32; off; off >>= 1) {
#pragma unroll
    for (int t = 0; t < TT; ++t) lc[t] += __shfl_xor(lc[t], off);
  }
  if ((tid & 63) == 0) {
#pragma unroll
    for (int t = 0; t < TT; ++t) red[tid >> 6][t] = lc[t];
  }
  __syncthreads();
  if (tid < TT) beta[t0 + tid] = red[0][tid] + red[1][tid] + red[2][tid] + red[3][tid];
}

// ---------------- softmax over beta ----------------
__global__ void softmax_kernel(const float* __restrict__ beta, float* __restrict__ alfa, int n) {
  __shared__ float sm[8];
  int tid = threadIdx.x, lane = tid & 63, wv = tid >> 6;
  float m = -3.4e38f;
  for (int i = tid; i < n; i += 256) m = fmaxf(m, beta[i]);
  for (int off = 32; off; off >>= 1) m = fmaxf(m, __shfl_xor(m, off));
  if (lane == 0) sm[wv] = m;
  __syncthreads();
  float M = fmaxf(fmaxf(sm[0], sm[1]), fmaxf(sm[2], sm[3]));
  float s = 0.f;
  for (int i = tid; i < n; i += 256) s += expf(beta[i] - M);
  for (int off = 32; off; off >>= 1) s += __shfl_xor(s, off);
  if (lane == 0) sm[4 + wv] = s;
  __syncthreads();
  float inv = 1.f / (sm[4] + sm[5] + sm[6] + sm[7]);
  for (int i = tid; i < n; i += 256) alfa[i] = expf(beta[i] - M) * inv;
}

// ---------------- s[h] = sum_t alfa[t]*O[t][h] ----------------
__global__ void svec_kernel(const float* __restrict__ alfa, const float* __restrict__ hsl,
                            const float* __restrict__ hsr, float* __restrict__ svec, int n) {
  __shared__ float red[4][64];
  int h = blockIdx.x * 64 + (threadIdx.x & 63);
  int ts = threadIdx.x >> 6;
  float s = 0.f;
  for (int t = ts; t < n; t += 4)
    s += alfa[t] * hsl[(size_t)t * HDIM + h] * hsr[(size_t)t * HDIM + h];
  red[ts][threadIdx.x & 63] = s;
  __syncthreads();
  if (threadIdx.x < 64)
    svec[blockIdx.x * 64 + threadIdx.x] =
        red[0][threadIdx.x] + red[1][threadIdx.x] + red[2][threadIdx.x] + red[3][threadIdx.x];
}

// ---------------- out[r] = lin2_w[r] . s + lin2_b[r] ----------------
__global__ void final_kernel(const float* __restrict__ svec, const float* __restrict__ l2w,
                             const float* __restrict__ l2b, float* __restrict__ out) {
  int r = threadIdx.x >> 6, lane = threadIdx.x & 63;
  float s = 0.f;
  for (int k = lane; k < HDIM; k += 64) s += l2w[(size_t)r * HDIM + k] * svec[k];
  for (int off = 32; off; off >>= 1) s += __shfl_xor(s, off);
  if (lane == 0) out[r] = s + l2b[r];
}

extern "C" void kernel_launch(void* const* d_in, const int* in_sizes, int n_in,
                              void* d_out, int out_size, void* d_ws, size_t ws_size,
                              hipStream_t stream) {
  const int* x = (const int*)d_in[0];
  const int* tstart = (const int*)d_in[1];
  const int* tend = (const int*)d_in[2];
  const float* emb = (const float*)d_in[3];
  const float* wih_l = (const float*)d_in[4];
  const float* whh_l = (const float*)d_in[5];
  const float* bih_l = (const float*)d_in[6];
  const float* bhh_l = (const float*)d_in[7];
  const float* wih_r = (const float*)d_in[8];
  const float* whh_r = (const float*)d_in[9];
  const float* bih_r = (const float*)d_in[10];
  const float* bhh_r = (const float*)d_in[11];
  const float* l1w = (const float*)d_in[12];
  const float* l1b = (const float*)d_in[13];
  const float* u = (const float*)d_in[14];
  const float* l2w = (const float*)d_in[15];
  const float* l2b = (const float*)d_in[16];
  const int n = in_sizes[0];  // 2048
  (void)n_in; (void)out_size; (void)ws_size;

  float* ws = (float*)d_ws;
  float* target = ws;                     // 1024
  float* seqfl = ws + 1024;               // 1024
  float* seqfr = ws + 2048;               // 1024
  float* glc = ws + 3072;                 // 4096
  float* glf = glc + 4096;                // 4096
  float* grc = glf + 4096;                // 4096
  float* grf = grc + 4096;                // 4096
  float* hbuf = grf + 4096;               // 2*1024
  float* hsl = hbuf + 2048;               // n*1024
  float* hsr = hsl + (size_t)n * HDIM;    // n*1024
  float* L1T = hsr + (size_t)n * HDIM;    // 1024*1024
  float* beta = L1T + (size_t)HDIM * HDIM;  // n
  float* alfa = beta + n;                 // n
  float* svec = alfa + n;                 // 1024
  int* flags = (int*)(svec + 1024);       // NWG (padded to 256)
  int* convf = flags + 256;               // (2n/KCHK)*NWG

  setup_kernel<<<1, 1024, 0, stream>>>(x, tstart, tend, emb, target, seqfl, seqfr, hbuf, flags, n);
  gateconst_kernel<<<dim3(1024, 2), 256, 0, stream>>>(wih_l, bih_l, bhh_l, wih_r, bih_r, bhh_r,
                                                      target, seqfl, seqfr, glc, glf, grc, grf);
  RecArgs ra;
  ra.whh_l = whh_l; ra.whh_r = whh_r;
  ra.glc = glc; ra.glf = glf; ra.grc = grc; ra.grf = grf;
  ra.hbuf = hbuf; ra.hsl = hsl; ra.hsr = hsr;
  ra.flags = flags; ra.convf = convf;
  ra.pstart = tstart; ra.pend = tend; ra.n = n;
  void* kargs[] = {(void*)&ra};
  hipLaunchCooperativeKernel((const void*)rec_kernel, dim3(NWG), dim3(TPB), kargs, 0, stream);

  transpose_kernel<<<dim3(32, 32), 256, 0, stream>>>(l1w, L1T);
  beta_kernel<<<dim3(n / TT), 256, 0, stream>>>(hsl, hsr, L1T, l1b, u, beta);
  softmax_kernel<<<1, 256, 0, stream>>>(beta, alfa, n);
  svec_kernel<<<16, 256, 0, stream>>>(alfa, hsl, hsr, svec, n);
  final_kernel<<<1, 192, 0, stream>>>(svec, l2w, l2b, (float*)d_out);
}

// Round 2
// 32253.015 us; speedup vs baseline: 1.1542x; 1.1542x over previous
//
#include <hip/hip_runtime.h>
#include <math.h>

#define HDIM 1024
#define NWG 128
#define TPB 256
#define KCHK 8

struct RecArgs {
  const float* whh_l; const float* whh_r;
  const float* glc; const float* glf; const float* grc; const float* grf;
  float* hbuf;        // [2][HDIM]
  float* hsl;         // [n][HDIM]
  float* hsr;         // [n][HDIM]
  int* flags;         // [NWG]
  int* convf;         // [ncp][NWG], write-once per slot, pre-zeroed
  const int* pstart; const int* pend;
  int n;
};

// ---------------- setup: target vector, special rows, zero state ----------------
__global__ void setup_kernel(const int* __restrict__ x, const int* ts, const int* te,
                             const float* __restrict__ emb,
                             float* target, float* seqfl, float* seqfr,
                             float* hbuf, int* flags, int n) {
  int e = threadIdx.x;  // 0..1023
  int start = ts[0], end = te[0];
  int first_l = (start > 0) ? 0 : (end + 1);
  int first_r = (end < n - 1) ? (n - 1) : (start - 1);
  int fl = min(max(first_l, 0), n - 1);
  int fr = min(max(first_r, 0), n - 1);
  float sum = 0.f;
  for (int p = start; p <= end; ++p) sum += emb[(size_t)x[p] * HDIM + e];
  target[e] = sum / (float)(end - start + 1);
  seqfl[e] = emb[(size_t)x[fl] * HDIM + e];
  seqfr[e] = emb[(size_t)x[fr] * HDIM + e];
  hbuf[e] = 0.f;
  hbuf[HDIM + e] = 0.f;
  if (e < NWG) flags[e] = 0;
}

// ---------------- gate-constant vectors: w_ih@v + b_ih + b_hh ----------------
__global__ __launch_bounds__(256) void gateconst_kernel(
    const float* __restrict__ wih_l, const float* bih_l, const float* bhh_l,
    const float* __restrict__ wih_r, const float* bih_r, const float* bhh_r,
    const float* __restrict__ target, const float* __restrict__ seqfl,
    const float* __restrict__ seqfr,
    float* glc, float* glf, float* grc, float* grf) {
  int side = blockIdx.y;
  const float* wih = side ? wih_r : wih_l;
  const float* bih = side ? bih_r : bih_l;
  const float* bhh = side ? bhh_r : bhh_l;
  const float* sf = side ? seqfr : seqfl;
  float* outc = side ? grc : glc;
  float* outf = side ? grf : glf;
  int wv = threadIdx.x >> 6, lane = threadIdx.x & 63;
  int r = blockIdx.x * 4 + wv;  // 0..4095
  const float4* wrow = (const float4*)(wih + (size_t)r * HDIM);
  const float4* tg4 = (const float4*)target;
  const float4* sf4 = (const float4*)sf;
  float dc = 0.f, df = 0.f;
#pragma unroll
  for (int k = 0; k < 4; ++k) {
    float4 w4 = wrow[lane + 64 * k];
    float4 t4 = tg4[lane + 64 * k];
    float4 s4 = sf4[lane + 64 * k];
    dc += w4.x * t4.x + w4.y * t4.y + w4.z * t4.z + w4.w * t4.w;
    df += w4.x * s4.x + w4.y * s4.y + w4.z * s4.z + w4.w * s4.w;
  }
  for (int off = 32; off; off >>= 1) {
    dc += __shfl_xor(dc, off);
    df += __shfl_xor(df, off);
  }
  if (lane == 0) {
    float bb = bih[r] + bhh[r];
    outc[r] = dc + bb;
    outf[r] = df + bb;
  }
}

// ---------------- persistent cooperative recurrence ----------------
// Sync protocol per step (all agent scope):
//   producer (wave0): relaxed write-through h stores -> release fence -> relaxed flag store
//   consumer (wave0): relaxed poll on flags -> ONE acquire fence -> plain h loads
// Convergence: bitwise period-2 fixed point of the global (h,c) state =>
// exact periodic fill of the remaining trajectory (bit-identical results).
__global__ __launch_bounds__(TPB, 1) void rec_kernel(RecArgs a) {
  const int w = blockIdx.x;
  const int tid = threadIdx.x;
  const int lane = tid & 63;
  const int wave = tid >> 6;
  const int half = lane >> 5;
  const int rloc = lane & 31;          // local row 0..31
  const int cb = wave * 2 + half;      // column block 0..7
  const int gate = rloc >> 3;          // 0..3 (i,f,g,o)
  const int j = rloc & 7;              // local h index 0..7
  const int col0 = cb * 128;
  const int R = gate * HDIM + w * 8 + j;  // global gate row
  const int n = a.n;

  __shared__ float lds_part[8][32];
  __shared__ float lds_h8[2][8];   // [parity][unit]: h at last step of that parity
  __shared__ int lds_ctrl;

  const int start = a.pstart[0];
  const int end = a.pend[0];
  const int first_l = (start > 0) ? 0 : (end + 1);
  const int first_r = (end < n - 1) ? (n - 1) : (start - 1);

  float4 wreg[32];
  // owner-lane (wave0, lane<8) state for unit w*8+j
  float cstate = 0.f, hprev = 0.f;
  float hp0 = 0.f, hp1 = 0.f, cp0 = 0.f, cp1 = 0.f;  // parity history (t-1 / t-2)

  for (int pass = 0; pass < 2; ++pass) {
    const float* whh = pass ? a.whh_r : a.whh_l;
    const float* gcv = pass ? a.grc : a.glc;
    const float* gfv = pass ? a.grf : a.glf;
    float* hsout = pass ? a.hsr : a.hsl;
    const int tspecial = pass ? (n - 1 - first_r) : first_l;
    const int sbase = pass * n;

    {  // load this pass's recurrent weights into registers
      const float4* wrow = (const float4*)(whh + (size_t)R * HDIM + col0);
#pragma unroll
      for (int k = 0; k < 32; ++k) wreg[k] = wrow[k];
    }
    float my_gc = 0.f, my_gf = 0.f;
    if (wave == 0 && lane < 32) { my_gc = gcv[R]; my_gf = gfv[R]; }
    // re-seed parity history at pass start (values only used after t>=3)
    hp0 = hp1 = hprev; cp0 = cp1 = cstate;

    bool fin = false;
    for (int t = 0; t < n && !fin; ++t) {
      const int s = sbase + t;
      if (wave == 0) {
        if (s > 0) {
          int guard = 0;
          for (;;) {
            int f1 = __hip_atomic_load(&a.flags[lane], __ATOMIC_RELAXED, __HIP_MEMORY_SCOPE_AGENT);
            int f2 = __hip_atomic_load(&a.flags[lane + 64], __ATOMIC_RELAXED, __HIP_MEMORY_SCOPE_AGENT);
            if (__all(f1 >= s && f2 >= s)) break;
            if (++guard > 50000000) break;  // anti-hang safety
          }
        }
        __builtin_amdgcn_fence(__ATOMIC_ACQUIRE, "agent");  // one inv per step
        int convdec = 0;
        if (t > 0 && (t % KCHK) == 0 && (t - 1) > tspecial + 2) {
          const int cp = s / KCHK - 1;  // written at step s-1 by all WGs
          int c1 = a.convf[(size_t)cp * NWG + lane];
          int c2 = a.convf[(size_t)cp * NWG + lane + 64];
          convdec = __all(c1 != 0 && c2 != 0);
        }
        if (lane == 0) lds_ctrl = convdec;
      }
      __syncthreads();  // B1
      const int convdec = lds_ctrl;

      if (convdec) {
        // Global state is period-2 from step t-2 on: h(t') == lds_h8[t'&1].
        const int col = tid & 7;
        for (int tt = t + (tid >> 3); tt < n; tt += 32)
          __builtin_nontemporal_store(lds_h8[tt & 1][col],
                                      &hsout[(size_t)tt * HDIM + w * 8 + col]);
        if (wave == 0 && lane < 8) {
          float hlast = ((n - 1) & 1) ? hp1 : hp0;  // h(n-1)
          float clast = ((n - 1) & 1) ? cp1 : cp0;  // c(n-1)
          cstate = clast; hprev = hlast;
          __hip_atomic_store(&a.hbuf[(size_t)(n & 1) * HDIM + w * 8 + j], hlast,
                             __ATOMIC_RELAXED, __HIP_MEMORY_SCOPE_AGENT);
        }
        if (wave == 0) __builtin_amdgcn_fence(__ATOMIC_RELEASE, "agent");
        if (tid == 0)
          __hip_atomic_store(&a.flags[w], sbase + n, __ATOMIC_RELAXED, __HIP_MEMORY_SCOPE_AGENT);
        fin = true;
        continue;
      }

      {  // partial dot: rows rloc, cols [col0, col0+128)
        const float4* __restrict__ h4 =
            (const float4*)(a.hbuf + (size_t)(s & 1) * HDIM + col0);
        float s0 = 0.f, s1 = 0.f, s2 = 0.f, s3 = 0.f;
#pragma unroll
        for (int k = 0; k < 32; k += 4) {
          float4 ha = h4[k + 0], hb = h4[k + 1], hc = h4[k + 2], hd = h4[k + 3];
          s0 += wreg[k + 0].x * ha.x + wreg[k + 0].y * ha.y + wreg[k + 0].z * ha.z + wreg[k + 0].w * ha.w;
          s1 += wreg[k + 1].x * hb.x + wreg[k + 1].y * hb.y + wreg[k + 1].z * hb.z + wreg[k + 1].w * hb.w;
          s2 += wreg[k + 2].x * hc.x + wreg[k + 2].y * hc.y + wreg[k + 2].z * hc.z + wreg[k + 2].w * hc.w;
          s3 += wreg[k + 3].x * hd.x + wreg[k + 3].y * hd.y + wreg[k + 3].z * hd.z + wreg[k + 3].w * hd.w;
        }
        lds_part[cb][rloc] = (s0 + s1) + (s2 + s3);
      }
      __syncthreads();  // B2

      if (wave == 0) {
        float sum = 0.f;
        if (lane < 32) {
#pragma unroll
          for (int b = 0; b < 8; ++b) sum += lds_part[b][rloc];
          sum += (t == tspecial) ? my_gf : my_gc;
        }
        // gate broadcast via shuffle (no LDS, no extra barrier)
        float gi = __shfl(sum, j);
        float gf2 = __shfl(sum, 8 + j);
        float gg = __shfl(sum, 16 + j);
        float go = __shfl(sum, 24 + j);
        int mystable = 1;
        if (lane < 8) {
          float iv = 1.f / (1.f + expf(-gi));
          float fv = 1.f / (1.f + expf(-gf2));
          float gv = tanhf(gg);
          float ov = 1.f / (1.f + expf(-go));
          float cnew = fv * cstate + iv * gv;
          float hn = ov * tanhf(cnew);
          float h2v = (t & 1) ? hp1 : hp0;  // h(t-2)
          float c2v = (t & 1) ? cp1 : cp0;  // c(t-2)
          mystable = (__float_as_uint(hn) == __float_as_uint(h2v)) &&
                     (__float_as_uint(cnew) == __float_as_uint(c2v));
          if (t & 1) { hp1 = hn; cp1 = cnew; } else { hp0 = hn; cp0 = cnew; }
          cstate = cnew; hprev = hn;
          __hip_atomic_store(&a.hbuf[(size_t)((s + 1) & 1) * HDIM + w * 8 + j], hn,
                             __ATOMIC_RELAXED, __HIP_MEMORY_SCOPE_AGENT);
          __builtin_nontemporal_store(hn, &hsout[(size_t)t * HDIM + w * 8 + j]);
          lds_h8[t & 1][j] = hn;
        }
        int allst = __all(mystable);
        if (lane == 0 && ((t + 1) % KCHK) == 0) {
          const int cp = (s + 1) / KCHK - 1;
          __hip_atomic_store(&a.convf[(size_t)cp * NWG + w],
                             (allst && t > tspecial + 2) ? 1 : 0,
                             __ATOMIC_RELAXED, __HIP_MEMORY_SCOPE_AGENT);
        }
        __builtin_amdgcn_fence(__ATOMIC_RELEASE, "agent");  // h at LLC before flag
        if (lane == 0)
          __hip_atomic_store(&a.flags[w], s + 1, __ATOMIC_RELAXED, __HIP_MEMORY_SCOPE_AGENT);
      }
      // waves 1..3 loop straight to B1 of the next step
    }
  }
}

// ---------------- lin1_w transpose: L1T[k][j] = lin1_w[j][k] ----------------
__global__ void transpose_kernel(const float* __restrict__ A, float* __restrict__ AT) {
  __shared__ float tile[32][33];
  int j0 = blockIdx.y * 32, k0 = blockIdx.x * 32;
  int tx = threadIdx.x & 31, ty = threadIdx.x >> 5;  // ty 0..7
  for (int r = ty; r < 32; r += 8) tile[r][tx] = A[(size_t)(j0 + r) * HDIM + k0 + tx];
  __syncthreads();
  for (int r = ty; r < 32; r += 8) AT[(size_t)(k0 + r) * HDIM + j0 + tx] = tile[tx][r];
}

// ---------------- beta[t] = sum_j u[j]*tanh( (O @ L1^T)[t][j] + b1[j] ) ----------------
#define TT 8
__global__ __launch_bounds__(256) void beta_kernel(const float* __restrict__ hsl,
                                                   const float* __restrict__ hsr,
                                                   const float* __restrict__ L1T,
                                                   const float* __restrict__ b1,
                                                   const float* __restrict__ u,
                                                   float* __restrict__ beta) {
  __shared__ float OT[128][9];
  __shared__ float red[4][TT];
  const int t0 = blockIdx.x * TT;
  const int tid = threadIdx.x;
  float acc[4][TT] = {};
  const float4 uv = ((const float4*)u)[tid];
  const float4 bv = ((const float4*)b1)[tid];

  for (int k0 = 0; k0 < HDIM; k0 += 128) {
    {  // stage O tile transposed: OT[k][t] = hsl*hsr
      int tt = tid >> 5, kk = tid & 31;
      const float4* l4 = (const float4*)(hsl + (size_t)(t0 + tt) * HDIM + k0);
      const float4* r4 = (const float4*)(hsr + (size_t)(t0 + tt) * HDIM + k0);
      float4 aa = l4[kk], bb = r4[kk];
      OT[kk * 4 + 0][tt] = aa.x * bb.x;
      OT[kk * 4 + 1][tt] = aa.y * bb.y;
      OT[kk * 4 + 2][tt] = aa.z * bb.z;
      OT[kk * 4 + 3][tt] = aa.w * bb.w;
    }
    __syncthreads();
    const float4* lp = (const float4*)L1T + (size_t)k0 * (HDIM / 4);
    for (int k = 0; k < 128; ++k) {
      float4 lv = lp[(size_t)k * (HDIM / 4) + tid];
      float ov[TT];
#pragma unroll
      for (int t = 0; t < TT; ++t) ov[t] = OT[k][t];
#pragma unroll
      for (int t = 0; t < TT; ++t) {
        acc[0][t] += lv.x * ov[t];
        acc[1][t] += lv.y * ov[t];
        acc[2][t] += lv.z * ov[t];
        acc[3][t] += lv.w * ov[t];
      }
    }
    __syncthreads();
  }
  float lc[TT];
#pragma unroll
  for (int t = 0; t < TT; ++t)
    lc[t] = uv.x * tanhf(acc[0][t] + bv.x) + uv.y * tanhf(acc[1][t] + bv.y) +
            uv.z * tanhf(acc[2][t] + bv.z) + uv.w * tanhf(acc[3][t] + bv.w);
  for (int off = 32; off; off >>= 1) {
#pragma unroll
    for (int t = 0; t < TT; ++t) lc[t] += __shfl_xor(lc[t], off);
  }
  if ((tid & 63) == 0) {
#pragma unroll
    for (int t = 0; t < TT; ++t) red[tid >> 6][t] = lc[t];
  }
  __syncthreads();
  if (tid < TT) beta[t0 + tid] = red[0][tid] + red[1][tid] + red[2][tid] + red[3][tid];
}

// ---------------- softmax over beta ----------------
__global__ void softmax_kernel(const float* __restrict__ beta, float* __restrict__ alfa, int n) {
  __shared__ float sm[8];
  int tid = threadIdx.x, lane = tid & 63, wv = tid >> 6;
  float m = -3.4e38f;
  for (int i = tid; i < n; i += 256) m = fmaxf(m, beta[i]);
  for (int off = 32; off; off >>= 1) m = fmaxf(m, __shfl_xor(m, off));
  if (lane == 0) sm[wv] = m;
  __syncthreads();
  float M = fmaxf(fmaxf(sm[0], sm[1]), fmaxf(sm[2], sm[3]));
  float s = 0.f;
  for (int i = tid; i < n; i += 256) s += expf(beta[i] - M);
  for (int off = 32; off; off >>= 1) s += __shfl_xor(s, off);
  if (lane == 0) sm[4 + wv] = s;
  __syncthreads();
  float inv = 1.f / (sm[4] + sm[5] + sm[6] + sm[7]);
  for (int i = tid; i < n; i += 256) alfa[i] = expf(beta[i] - M) * inv;
}

// ---------------- s[h] = sum_t alfa[t]*O[t][h] ----------------
__global__ void svec_kernel(const float* __restrict__ alfa, const float* __restrict__ hsl,
                            const float* __restrict__ hsr, float* __restrict__ svec, int n) {
  __shared__ float red[4][64];
  int h = blockIdx.x * 64 + (threadIdx.x & 63);
  int ts = threadIdx.x >> 6;
  float s = 0.f;
  for (int t = ts; t < n; t += 4)
    s += alfa[t] * hsl[(size_t)t * HDIM + h] * hsr[(size_t)t * HDIM + h];
  red[ts][threadIdx.x & 63] = s;
  __syncthreads();
  if (threadIdx.x < 64)
    svec[blockIdx.x * 64 + threadIdx.x] =
        red[0][threadIdx.x] + red[1][threadIdx.x] + red[2][threadIdx.x] + red[3][threadIdx.x];
}

// ---------------- out[r] = lin2_w[r] . s + lin2_b[r] ----------------
__global__ void final_kernel(const float* __restrict__ svec, const float* __restrict__ l2w,
                             const float* __restrict__ l2b, float* __restrict__ out) {
  int r = threadIdx.x >> 6, lane = threadIdx.x & 63;
  float s = 0.f;
  for (int k = lane; k < HDIM; k += 64) s += l2w[(size_t)r * HDIM + k] * svec[k];
  for (int off = 32; off; off >>= 1) s += __shfl_xor(s, off);
  if (lane == 0) out[r] = s + l2b[r];
}

extern "C" void kernel_launch(void* const* d_in, const int* in_sizes, int n_in,
                              void* d_out, int out_size, void* d_ws, size_t ws_size,
                              hipStream_t stream) {
  const int* x = (const int*)d_in[0];
  const int* tstart = (const int*)d_in[1];
  const int* tend = (const int*)d_in[2];
  const float* emb = (const float*)d_in[3];
  const float* wih_l = (const float*)d_in[4];
  const float* whh_l = (const float*)d_in[5];
  const float* bih_l = (const float*)d_in[6];
  const float* bhh_l = (const float*)d_in[7];
  const float* wih_r = (const float*)d_in[8];
  const float* whh_r = (const float*)d_in[9];
  const float* bih_r = (const float*)d_in[10];
  const float* bhh_r = (const float*)d_in[11];
  const float* l1w = (const float*)d_in[12];
  const float* l1b = (const float*)d_in[13];
  const float* u = (const float*)d_in[14];
  const float* l2w = (const float*)d_in[15];
  const float* l2b = (const float*)d_in[16];
  const int n = in_sizes[0];  // 2048
  (void)n_in; (void)out_size; (void)ws_size;

  float* ws = (float*)d_ws;
  float* target = ws;                     // 1024
  float* seqfl = ws + 1024;               // 1024
  float* seqfr = ws + 2048;               // 1024
  float* glc = ws + 3072;                 // 4096
  float* glf = glc + 4096;                // 4096
  float* grc = glf + 4096;                // 4096
  float* grf = grc + 4096;                // 4096
  float* hbuf = grf + 4096;               // 2*1024
  float* hsl = hbuf + 2048;               // n*1024
  float* hsr = hsl + (size_t)n * HDIM;    // n*1024
  float* L1T = hsr + (size_t)n * HDIM;    // 1024*1024
  float* beta = L1T + (size_t)HDIM * HDIM;  // n
  float* alfa = beta + n;                 // n
  float* svec = alfa + n;                 // 1024
  int* flags = (int*)(svec + 1024);       // NWG (padded to 256)
  // convf lives in the L1T region: rec_kernel finishes before transpose writes L1T
  int* convf = (int*)L1T;                 // (2n/KCHK)*NWG ints = 256 KB << 4 MB

  setup_kernel<<<1, 1024, 0, stream>>>(x, tstart, tend, emb, target, seqfl, seqfr, hbuf, flags, n);
  gateconst_kernel<<<dim3(1024, 2), 256, 0, stream>>>(wih_l, bih_l, bhh_l, wih_r, bih_r, bhh_r,
                                                      target, seqfl, seqfr, glc, glf, grc, grf);
  hipMemsetAsync(convf, 0, (size_t)(2 * n / KCHK) * NWG * sizeof(int), stream);

  RecArgs ra;
  ra.whh_l = whh_l; ra.whh_r = whh_r;
  ra.glc = glc; ra.glf = glf; ra.grc = grc; ra.grf = grf;
  ra.hbuf = hbuf; ra.hsl = hsl; ra.hsr = hsr;
  ra.flags = flags; ra.convf = convf;
  ra.pstart = tstart; ra.pend = tend; ra.n = n;
  void* kargs[] = {(void*)&ra};
  hipLaunchCooperativeKernel((const void*)rec_kernel, dim3(NWG), dim3(TPB), kargs, 0, stream);

  transpose_kernel<<<dim3(32, 32), 256, 0, stream>>>(l1w, L1T);
  beta_kernel<<<dim3(n / TT), 256, 0, stream>>>(hsl, hsr, L1T, l1b, u, beta);
  softmax_kernel<<<1, 256, 0, stream>>>(beta, alfa, n);
  svec_kernel<<<16, 256, 0, stream>>>(alfa, hsl, hsr, svec, n);
  final_kernel<<<1, 192, 0, stream>>>(svec, l2w, l2b, (float*)d_out);
}

// Round 3
// 10835.073 us; speedup vs baseline: 3.4356x; 2.9767x over previous
//
#include <hip/hip_runtime.h>
#include <math.h>

#define HDIM 1024
#define NWG 128
#define TPB 256

typedef unsigned long long u64;
typedef unsigned int u32;

struct RecArgs {
  const float* whh_l; const float* whh_r;
  const float* glc; const float* glf; const float* grc; const float* grf;
  u64* hq;            // [2][HDIM] tagged slots: low32 = tag | stable<<31, high32 = f32 bits
  float* hsl;         // [n][HDIM]
  float* hsr;         // [n][HDIM]
  const int* pstart; const int* pend;
  int n;
};

// ---------------- setup: target vector, special rows, tagged-state init ----------------
__global__ void setup_kernel(const int* __restrict__ x, const int* ts, const int* te,
                             const float* __restrict__ emb,
                             float* target, float* seqfl, float* seqfr,
                             u64* hq, int n) {
  int e = threadIdx.x;  // 0..1023
  int start = ts[0], end = te[0];
  int first_l = (start > 0) ? 0 : (end + 1);
  int first_r = (end < n - 1) ? (n - 1) : (start - 1);
  int fl = min(max(first_l, 0), n - 1);
  int fr = min(max(first_r, 0), n - 1);
  float sum = 0.f;
  for (int p = start; p <= end; ++p) sum += emb[(size_t)x[p] * HDIM + e];
  target[e] = sum / (float)(end - start + 1);
  seqfl[e] = emb[(size_t)x[fl] * HDIM + e];
  seqfr[e] = emb[(size_t)x[fr] * HDIM + e];
  // tag=0 (h input for step 0), value = 0.0f, stable=0 — both parities
  hq[e] = 0ull;
  hq[HDIM + e] = 0ull;
}

// ---------------- gate-constant vectors: w_ih@v + b_ih + b_hh ----------------
__global__ __launch_bounds__(256) void gateconst_kernel(
    const float* __restrict__ wih_l, const float* bih_l, const float* bhh_l,
    const float* __restrict__ wih_r, const float* bih_r, const float* bhh_r,
    const float* __restrict__ target, const float* __restrict__ seqfl,
    const float* __restrict__ seqfr,
    float* glc, float* glf, float* grc, float* grf) {
  int side = blockIdx.y;
  const float* wih = side ? wih_r : wih_l;
  const float* bih = side ? bih_r : bih_l;
  const float* bhh = side ? bhh_r : bhh_l;
  const float* sf = side ? seqfr : seqfl;
  float* outc = side ? grc : glc;
  float* outf = side ? grf : glf;
  int wv = threadIdx.x >> 6, lane = threadIdx.x & 63;
  int r = blockIdx.x * 4 + wv;  // 0..4095
  const float4* wrow = (const float4*)(wih + (size_t)r * HDIM);
  const float4* tg4 = (const float4*)target;
  const float4* sf4 = (const float4*)sf;
  float dc = 0.f, df = 0.f;
#pragma unroll
  for (int k = 0; k < 4; ++k) {
    float4 w4 = wrow[lane + 64 * k];
    float4 t4 = tg4[lane + 64 * k];
    float4 s4 = sf4[lane + 64 * k];
    dc += w4.x * t4.x + w4.y * t4.y + w4.z * t4.z + w4.w * t4.w;
    df += w4.x * s4.x + w4.y * s4.y + w4.z * s4.z + w4.w * s4.w;
  }
  for (int off = 32; off; off >>= 1) {
    dc += __shfl_xor(dc, off);
    df += __shfl_xor(df, off);
  }
  if (lane == 0) {
    float bb = bih[r] + bhh[r];
    outc[r] = dc + bb;
    outf[r] = df + bb;
  }
}

// ---------------- persistent cooperative recurrence ----------------
// Protocol: h values travel inside relaxed agent-scope 8B atomics (tag+payload),
// parity double-buffered. NO fences, NO cache-maintenance ops anywhere.
// tag monotone; tag > s observed by a poller can only mean convergence fast-forward.
// stable bit (tag MSB) = unit's (h,c) is bitwise period-2 => unanimous local consensus.
__global__ __launch_bounds__(TPB, 1) void rec_kernel(RecArgs a) {
  const int w = blockIdx.x;
  const int tid = threadIdx.x;
  const int wave = tid >> 6;
  const int lane = tid & 63;
  const int chunk = tid & 31;    // 32-col chunk of the k dimension
  const int rowgrp = tid >> 5;   // 0..7 -> local rows rowgrp*4..+3
  const int n = a.n;

  __shared__ float lds_h[HDIM];
  __shared__ float lds_part[32 * 36];  // [chunk][row] pitch 36 floats (16B-aligned rows)
  __shared__ float lds_h8[2][8];       // [local parity][unit]
  __shared__ int lds_conv[4];

  const int start = a.pstart[0];
  const int end = a.pend[0];
  const int first_l = (start > 0) ? 0 : (end + 1);
  const int first_r = (end < n - 1) ? (n - 1) : (start - 1);

  float4 wreg[4][8];  // constant-indexed only => guaranteed VGPR residency
  float cstate = 0.f;
  float hp0 = 0.f, hp1 = 0.f, cp0 = 0.f, cp1 = 0.f;  // parity history

  for (int pass = 0; pass < 2; ++pass) {
    const float* whh = pass ? a.whh_r : a.whh_l;
    const float* gcv = pass ? a.grc : a.glc;
    const float* gfv = pass ? a.grf : a.glf;
    float* hsout = pass ? a.hsr : a.hsl;
    const int tspecial = pass ? (n - 1 - first_r) : first_l;
    const int sbase = pass * n;

    // Load weights, pre-rotated by chunk so the LDS read swizzle needs no
    // dynamic register indexing: wreg[r][i] holds cols chunk*32 + ((i+chunk)&7)*4 ..
#pragma unroll
    for (int r = 0; r < 4; ++r) {
      const int lr = rowgrp * 4 + r;
      const int grow = (lr >> 3) * HDIM + w * 8 + (lr & 7);
      const float4* wr = (const float4*)(whh + (size_t)grow * HDIM) + chunk * 8;
#pragma unroll
      for (int i = 0; i < 8; ++i) wreg[r][i] = wr[(i + chunk) & 7];
    }
    float my_gc = 0.f, my_gf = 0.f;
    if (wave == 0 && lane < 32) {
      const int R = (lane >> 3) * HDIM + w * 8 + (lane & 7);
      my_gc = gcv[R];
      my_gf = gfv[R];
    }

    bool fin = false;
    for (int t = 0; t < n && !fin; ++t) {
      const int s = sbase + t;
      // ---- poll tagged slots (4 units per lane, all 1024 covered by the WG) ----
      const u64* slot = a.hq + (size_t)(s & 1) * HDIM + tid * 4;
      u64 v0, v1, v2, v3;
      u32 t0, t1, t2, t3;
      int guard = 0;
      for (;;) {
        v0 = __hip_atomic_load(slot + 0, __ATOMIC_RELAXED, __HIP_MEMORY_SCOPE_AGENT);
        v1 = __hip_atomic_load(slot + 1, __ATOMIC_RELAXED, __HIP_MEMORY_SCOPE_AGENT);
        v2 = __hip_atomic_load(slot + 2, __ATOMIC_RELAXED, __HIP_MEMORY_SCOPE_AGENT);
        v3 = __hip_atomic_load(slot + 3, __ATOMIC_RELAXED, __HIP_MEMORY_SCOPE_AGENT);
        t0 = (u32)v0 & 0x7fffffffu; t1 = (u32)v1 & 0x7fffffffu;
        t2 = (u32)v2 & 0x7fffffffu; t3 = (u32)v3 & 0x7fffffffu;
        int ok = (t0 >= (u32)s) && (t1 >= (u32)s) && (t2 >= (u32)s) && (t3 >= (u32)s);
        if (__all(ok)) break;
        if (++guard > 4000000) break;  // anti-hang safety
      }
      int anyg = (t0 > (u32)s) || (t1 > (u32)s) || (t2 > (u32)s) || (t3 > (u32)s);
      int stall = (int)((((u32)v0) >> 31) & (((u32)v1) >> 31) &
                        (((u32)v2) >> 31) & (((u32)v3) >> 31));
      int wany = __any(anyg);
      int wall = __all(stall);
      if (lane == 0) lds_conv[wave] = (wall << 1) | wany;
      // publish the 4 polled h values into LDS
      float4 hv;
      hv.x = __uint_as_float((u32)(v0 >> 32));
      hv.y = __uint_as_float((u32)(v1 >> 32));
      hv.z = __uint_as_float((u32)(v2 >> 32));
      hv.w = __uint_as_float((u32)(v3 >> 32));
      ((float4*)lds_h)[tid] = hv;
      __syncthreads();  // B1
      const int c0 = lds_conv[0], c1 = lds_conv[1], c2 = lds_conv[2], c3 = lds_conv[3];
      const int convdec = ((c0 | c1 | c2 | c3) & 1) | (((c0 & c1 & c2 & c3) >> 1) & 1);

      if (convdec) {
        // Global state is bitwise period-2: fill remaining rows with the two phases.
        const int col = tid & 7;
        for (int tt = t + (tid >> 3); tt < n; tt += 32)
          __builtin_nontemporal_store(lds_h8[tt & 1][col],
                                      &hsout[(size_t)tt * HDIM + w * 8 + col]);
        if (wave == 0 && lane < 8) {
          float hlast = ((n - 1) & 1) ? hp1 : hp0;  // h(n-1)
          float clast = ((n - 1) & 1) ? cp1 : cp0;  // c(n-1)
          cstate = clast;
          u64 pub = (u64)(u32)(sbase + n) | ((u64)__float_as_uint(hlast) << 32);
          __hip_atomic_store(&a.hq[(size_t)((sbase + n) & 1) * HDIM + w * 8 + lane], pub,
                             __ATOMIC_RELAXED, __HIP_MEMORY_SCOPE_AGENT);
        }
        __syncthreads();
        fin = true;
        continue;
      }

      // ---- partial dot: 4 rows x 32 cols per lane, h from LDS (swizzled) ----
      float acc0 = 0.f, acc1 = 0.f, acc2 = 0.f, acc3 = 0.f;
      const float4* lh4 = (const float4*)lds_h + chunk * 8;
#pragma unroll
      for (int i = 0; i < 8; ++i) {
        float4 h4 = lh4[(i + chunk) & 7];
        acc0 += wreg[0][i].x * h4.x + wreg[0][i].y * h4.y + wreg[0][i].z * h4.z + wreg[0][i].w * h4.w;
        acc1 += wreg[1][i].x * h4.x + wreg[1][i].y * h4.y + wreg[1][i].z * h4.z + wreg[1][i].w * h4.w;
        acc2 += wreg[2][i].x * h4.x + wreg[2][i].y * h4.y + wreg[2][i].z * h4.z + wreg[2][i].w * h4.w;
        acc3 += wreg[3][i].x * h4.x + wreg[3][i].y * h4.y + wreg[3][i].z * h4.z + wreg[3][i].w * h4.w;
      }
      {
        float4 p; p.x = acc0; p.y = acc1; p.z = acc2; p.w = acc3;
        *(float4*)&lds_part[chunk * 36 + rowgrp * 4] = p;
      }
      __syncthreads();  // B2

      if (wave == 0) {
        float sum = 0.f;
        if (lane < 32) {
#pragma unroll
          for (int cc = 0; cc < 32; ++cc) sum += lds_part[cc * 36 + lane];
          sum += (t == tspecial) ? my_gf : my_gc;
        }
        const int j = lane & 7;
        float gi = __shfl(sum, j);
        float gf2 = __shfl(sum, 8 + j);
        float gg = __shfl(sum, 16 + j);
        float go = __shfl(sum, 24 + j);
        if (lane < 8) {
          float iv = 1.f / (1.f + expf(-gi));
          float fv = 1.f / (1.f + expf(-gf2));
          float gv = tanhf(gg);
          float ov = 1.f / (1.f + expf(-go));
          float cnew = fv * cstate + iv * gv;
          float hn = ov * tanhf(cnew);
          float h2 = (t & 1) ? hp1 : hp0;   // h(t-2)
          float c2v = (t & 1) ? cp1 : cp0;  // c(t-2)
          int stab = (__float_as_uint(hn) == __float_as_uint(h2)) &&
                     (__float_as_uint(cnew) == __float_as_uint(c2v)) &&
                     (t > tspecial + 2) && (t >= 3);
          if (t & 1) { hp1 = hn; cp1 = cnew; } else { hp0 = hn; cp0 = cnew; }
          cstate = cnew;
          lds_h8[t & 1][j] = hn;
          __builtin_nontemporal_store(hn, &hsout[(size_t)t * HDIM + w * 8 + j]);
          u32 tagw = (u32)(s + 1) | ((u32)stab << 31);
          u64 pub = (u64)tagw | ((u64)__float_as_uint(hn) << 32);
          __hip_atomic_store(&a.hq[(size_t)((s + 1) & 1) * HDIM + w * 8 + j], pub,
                             __ATOMIC_RELAXED, __HIP_MEMORY_SCOPE_AGENT);
        }
      }
      // waves 1..3 proceed straight to the next step's poll
    }
  }
}

// ---------------- lin1_w transpose: L1T[k][j] = lin1_w[j][k] ----------------
__global__ void transpose_kernel(const float* __restrict__ A, float* __restrict__ AT) {
  __shared__ float tile[32][33];
  int j0 = blockIdx.y * 32, k0 = blockIdx.x * 32;
  int tx = threadIdx.x & 31, ty = threadIdx.x >> 5;  // ty 0..7
  for (int r = ty; r < 32; r += 8) tile[r][tx] = A[(size_t)(j0 + r) * HDIM + k0 + tx];
  __syncthreads();
  for (int r = ty; r < 32; r += 8) AT[(size_t)(k0 + r) * HDIM + j0 + tx] = tile[tx][r];
}

// ---------------- beta[t] = sum_j u[j]*tanh( (O @ L1^T)[t][j] + b1[j] ) ----------------
#define TT 8
__global__ __launch_bounds__(256) void beta_kernel(const float* __restrict__ hsl,
                                                   const float* __restrict__ hsr,
                                                   const float* __restrict__ L1T,
                                                   const float* __restrict__ b1,
                                                   const float* __restrict__ u,
                                                   float* __restrict__ beta) {
  __shared__ float OT[128][9];
  __shared__ float red[4][TT];
  const int t0 = blockIdx.x * TT;
  const int tid = threadIdx.x;
  float acc[4][TT] = {};
  const float4 uv = ((const float4*)u)[tid];
  const float4 bv = ((const float4*)b1)[tid];

  for (int k0 = 0; k0 < HDIM; k0 += 128) {
    {  // stage O tile transposed: OT[k][t] = hsl*hsr
      int tt = tid >> 5, kk = tid & 31;
      const float4* l4 = (const float4*)(hsl + (size_t)(t0 + tt) * HDIM + k0);
      const float4* r4 = (const float4*)(hsr + (size_t)(t0 + tt) * HDIM + k0);
      float4 aa = l4[kk], bb = r4[kk];
      OT[kk * 4 + 0][tt] = aa.x * bb.x;
      OT[kk * 4 + 1][tt] = aa.y * bb.y;
      OT[kk * 4 + 2][tt] = aa.z * bb.z;
      OT[kk * 4 + 3][tt] = aa.w * bb.w;
    }
    __syncthreads();
    const float4* lp = (const float4*)L1T + (size_t)k0 * (HDIM / 4);
    for (int k = 0; k < 128; ++k) {
      float4 lv = lp[(size_t)k * (HDIM / 4) + tid];
      float ov[TT];
#pragma unroll
      for (int t = 0; t < TT; ++t) ov[t] = OT[k][t];
#pragma unroll
      for (int t = 0; t < TT; ++t) {
        acc[0][t] += lv.x * ov[t];
        acc[1][t] += lv.y * ov[t];
        acc[2][t] += lv.z * ov[t];
        acc[3][t] += lv.w * ov[t];
      }
    }
    __syncthreads();
  }
  float lc[TT];
#pragma unroll
  for (int t = 0; t < TT; ++t)
    lc[t] = uv.x * tanhf(acc[0][t] + bv.x) + uv.y * tanhf(acc[1][t] + bv.y) +
            uv.z * tanhf(acc[2][t] + bv.z) + uv.w * tanhf(acc[3][t] + bv.w);
  for (int off = 32; off; off >>= 1) {
#pragma unroll
    for (int t = 0; t < TT; ++t) lc[t] += __shfl_xor(lc[t], off);
  }
  if ((tid & 63) == 0) {
#pragma unroll
    for (int t = 0; t < TT; ++t) red[tid >> 6][t] = lc[t];
  }
  __syncthreads();
  if (tid < TT) beta[t0 + tid] = red[0][tid] + red[1][tid] + red[2][tid] + red[3][tid];
}

// ---------------- softmax over beta ----------------
__global__ void softmax_kernel(const float* __restrict__ beta, float* __restrict__ alfa, int n) {
  __shared__ float sm[8];
  int tid = threadIdx.x, lane = tid & 63, wv = tid >> 6;
  float m = -3.4e38f;
  for (int i = tid; i < n; i += 256) m = fmaxf(m, beta[i]);
  for (int off = 32; off; off >>= 1) m = fmaxf(m, __shfl_xor(m, off));
  if (lane == 0) sm[wv] = m;
  __syncthreads();
  float M = fmaxf(fmaxf(sm[0], sm[1]), fmaxf(sm[2], sm[3]));
  float s = 0.f;
  for (int i = tid; i < n; i += 256) s += expf(beta[i] - M);
  for (int off = 32; off; off >>= 1) s += __shfl_xor(s, off);
  if (lane == 0) sm[4 + wv] = s;
  __syncthreads();
  float inv = 1.f / (sm[4] + sm[5] + sm[6] + sm[7]);
  for (int i = tid; i < n; i += 256) alfa[i] = expf(beta[i] - M) * inv;
}

// ---------------- s[h] = sum_t alfa[t]*O[t][h] ----------------
__global__ void svec_kernel(const float* __restrict__ alfa, const float* __restrict__ hsl,
                            const float* __restrict__ hsr, float* __restrict__ svec, int n) {
  __shared__ float red[4][64];
  int h = blockIdx.x * 64 + (threadIdx.x & 63);
  int ts = threadIdx.x >> 6;
  float s = 0.f;
  for (int t = ts; t < n; t += 4)
    s += alfa[t] * hsl[(size_t)t * HDIM + h] * hsr[(size_t)t * HDIM + h];
  red[ts][threadIdx.x & 63] = s;
  __syncthreads();
  if (threadIdx.x < 64)
    svec[blockIdx.x * 64 + threadIdx.x] =
        red[0][threadIdx.x] + red[1][threadIdx.x] + red[2][threadIdx.x] + red[3][threadIdx.x];
}

// ---------------- out[r] = lin2_w[r] . s + lin2_b[r] ----------------
__global__ void final_kernel(const float* __restrict__ svec, const float* __restrict__ l2w,
                             const float* __restrict__ l2b, float* __restrict__ out) {
  int r = threadIdx.x >> 6, lane = threadIdx.x & 63;
  float s = 0.f;
  for (int k = lane; k < HDIM; k += 64) s += l2w[(size_t)r * HDIM + k] * svec[k];
  for (int off = 32; off; off >>= 1) s += __shfl_xor(s, off);
  if (lane == 0) out[r] = s + l2b[r];
}

extern "C" void kernel_launch(void* const* d_in, const int* in_sizes, int n_in,
                              void* d_out, int out_size, void* d_ws, size_t ws_size,
                              hipStream_t stream) {
  const int* x = (const int*)d_in[0];
  const int* tstart = (const int*)d_in[1];
  const int* tend = (const int*)d_in[2];
  const float* emb = (const float*)d_in[3];
  const float* wih_l = (const float*)d_in[4];
  const float* whh_l = (const float*)d_in[5];
  const float* bih_l = (const float*)d_in[6];
  const float* bhh_l = (const float*)d_in[7];
  const float* wih_r = (const float*)d_in[8];
  const float* whh_r = (const float*)d_in[9];
  const float* bih_r = (const float*)d_in[10];
  const float* bhh_r = (const float*)d_in[11];
  const float* l1w = (const float*)d_in[12];
  const float* l1b = (const float*)d_in[13];
  const float* u = (const float*)d_in[14];
  const float* l2w = (const float*)d_in[15];
  const float* l2b = (const float*)d_in[16];
  const int n = in_sizes[0];  // 2048
  (void)n_in; (void)out_size; (void)ws_size;

  float* ws = (float*)d_ws;
  float* target = ws;                     // 1024
  float* seqfl = ws + 1024;               // 1024
  float* seqfr = ws + 2048;               // 1024
  float* glc = ws + 3072;                 // 4096
  float* glf = glc + 4096;                // 4096
  float* grc = glf + 4096;                // 4096
  float* grf = grc + 4096;                // 4096
  u64* hq = (u64*)(grf + 4096);           // 2*1024 u64 (8B aligned: offset is 8*4096B)
  float* hsl = (float*)(hq + 2 * HDIM);   // n*1024
  float* hsr = hsl + (size_t)n * HDIM;    // n*1024
  float* L1T = hsr + (size_t)n * HDIM;    // 1024*1024
  float* beta = L1T + (size_t)HDIM * HDIM;  // n
  float* alfa = beta + n;                 // n
  float* svec = alfa + n;                 // 1024

  setup_kernel<<<1, 1024, 0, stream>>>(x, tstart, tend, emb, target, seqfl, seqfr, hq, n);
  gateconst_kernel<<<dim3(1024, 2), 256, 0, stream>>>(wih_l, bih_l, bhh_l, wih_r, bih_r, bhh_r,
                                                      target, seqfl, seqfr, glc, glf, grc, grf);
  RecArgs ra;
  ra.whh_l = whh_l; ra.whh_r = whh_r;
  ra.glc = glc; ra.glf = glf; ra.grc = grc; ra.grf = grf;
  ra.hq = hq; ra.hsl = hsl; ra.hsr = hsr;
  ra.pstart = tstart; ra.pend = tend; ra.n = n;
  void* kargs[] = {(void*)&ra};
  hipLaunchCooperativeKernel((const void*)rec_kernel, dim3(NWG), dim3(TPB), kargs, 0, stream);

  transpose_kernel<<<dim3(32, 32), 256, 0, stream>>>(l1w, L1T);
  beta_kernel<<<dim3(n / TT), 256, 0, stream>>>(hsl, hsr, L1T, l1b, u, beta);
  softmax_kernel<<<1, 256, 0, stream>>>(beta, alfa, n);
  svec_kernel<<<16, 256, 0, stream>>>(alfa, hsl, hsr, svec, n);
  final_kernel<<<1, 192, 0, stream>>>(svec, l2w, l2b, (float*)d_out);
}

// Round 4
// 1265.941 us; speedup vs baseline: 29.4049x; 8.5589x over previous
//
#include <hip/hip_runtime.h>
#include <math.h>

#define HDIM 1024
#define NWG 128
#define TPB 256
#define CONV_TOL 1.0e-7f

typedef unsigned long long u64;
typedef unsigned int u32;

struct RecArgs {
  const float* whh_l; const float* whh_r;
  const float* glc; const float* glf; const float* grc; const float* grf;
  u64* hq;            // [2][HDIM] tagged slots: low32 = tag | stable<<31, high32 = f32 bits
  float* hsl;         // [n][HDIM]
  float* hsr;         // [n][HDIM]
  const int* pstart; const int* pend;
  int n;
};

// ---------------- setup: target vector, special rows, tagged-state init ----------------
__global__ void setup_kernel(const int* __restrict__ x, const int* ts, const int* te,
                             const float* __restrict__ emb,
                             float* target, float* seqfl, float* seqfr,
                             u64* hq, int n) {
  int e = threadIdx.x;  // 0..1023
  int start = ts[0], end = te[0];
  int first_l = (start > 0) ? 0 : (end + 1);
  int first_r = (end < n - 1) ? (n - 1) : (start - 1);
  int fl = min(max(first_l, 0), n - 1);
  int fr = min(max(first_r, 0), n - 1);
  float sum = 0.f;
  for (int p = start; p <= end; ++p) sum += emb[(size_t)x[p] * HDIM + e];
  target[e] = sum / (float)(end - start + 1);
  seqfl[e] = emb[(size_t)x[fl] * HDIM + e];
  seqfr[e] = emb[(size_t)x[fr] * HDIM + e];
  // tag=0 (h input for step 0), value = 0.0f, stable=0 — both parities
  hq[e] = 0ull;
  hq[HDIM + e] = 0ull;
}

// ---------------- gate-constant vectors: w_ih@v + b_ih + b_hh ----------------
__global__ __launch_bounds__(256) void gateconst_kernel(
    const float* __restrict__ wih_l, const float* bih_l, const float* bhh_l,
    const float* __restrict__ wih_r, const float* bih_r, const float* bhh_r,
    const float* __restrict__ target, const float* __restrict__ seqfl,
    const float* __restrict__ seqfr,
    float* glc, float* glf, float* grc, float* grf) {
  int side = blockIdx.y;
  const float* wih = side ? wih_r : wih_l;
  const float* bih = side ? bih_r : bih_l;
  const float* bhh = side ? bhh_r : bhh_l;
  const float* sf = side ? seqfr : seqfl;
  float* outc = side ? grc : glc;
  float* outf = side ? grf : glf;
  int wv = threadIdx.x >> 6, lane = threadIdx.x & 63;
  int r = blockIdx.x * 4 + wv;  // 0..4095
  const float4* wrow = (const float4*)(wih + (size_t)r * HDIM);
  const float4* tg4 = (const float4*)target;
  const float4* sf4 = (const float4*)sf;
  float dc = 0.f, df = 0.f;
#pragma unroll
  for (int k = 0; k < 4; ++k) {
    float4 w4 = wrow[lane + 64 * k];
    float4 t4 = tg4[lane + 64 * k];
    float4 s4 = sf4[lane + 64 * k];
    dc += w4.x * t4.x + w4.y * t4.y + w4.z * t4.z + w4.w * t4.w;
    df += w4.x * s4.x + w4.y * s4.y + w4.z * s4.z + w4.w * s4.w;
  }
  for (int off = 32; off; off >>= 1) {
    dc += __shfl_xor(dc, off);
    df += __shfl_xor(df, off);
  }
  if (lane == 0) {
    float bb = bih[r] + bhh[r];
    outc[r] = dc + bb;
    outf[r] = df + bb;
  }
}

// ---------------- persistent cooperative recurrence ----------------
// Protocol: h values travel inside relaxed agent-scope 8B atomics (tag+payload),
// parity double-buffered. NO fences, NO cache-maintenance ops anywhere.
// tag monotone; tag > s observed by a poller can only mean convergence fast-forward.
// stable bit (tag MSB): unit's (h,c) changed by <= CONV_TOL vs two steps ago.
// Unanimous stable bits at one step => state is within ~1e-7 of the attractor;
// freeze the trajectory (fill remaining rows with the two parity phases).
__global__ __launch_bounds__(TPB, 1) void rec_kernel(RecArgs a) {
  const int w = blockIdx.x;
  const int tid = threadIdx.x;
  const int wave = tid >> 6;
  const int lane = tid & 63;
  const int chunk = tid & 31;    // 32-col chunk of the k dimension
  const int rowgrp = tid >> 5;   // 0..7 -> local rows rowgrp*4..+3
  const int n = a.n;

  __shared__ float lds_h[HDIM];
  __shared__ float lds_part[32 * 36];  // [chunk][row] pitch 36 floats (16B-aligned rows)
  __shared__ float lds_h8[2][8];       // [local parity][unit]
  __shared__ int lds_conv[4];

  const int start = a.pstart[0];
  const int end = a.pend[0];
  const int first_l = (start > 0) ? 0 : (end + 1);
  const int first_r = (end < n - 1) ? (n - 1) : (start - 1);

  float4 wreg[4][8];  // constant-indexed only => guaranteed VGPR residency
  float cstate = 0.f;
  float hp0 = 0.f, hp1 = 0.f, cp0 = 0.f, cp1 = 0.f;  // parity history

  for (int pass = 0; pass < 2; ++pass) {
    const float* whh = pass ? a.whh_r : a.whh_l;
    const float* gcv = pass ? a.grc : a.glc;
    const float* gfv = pass ? a.grf : a.glf;
    float* hsout = pass ? a.hsr : a.hsl;
    const int tspecial = pass ? (n - 1 - first_r) : first_l;
    const int sbase = pass * n;

    // Load weights, pre-rotated by chunk so the LDS read swizzle needs no
    // dynamic register indexing: wreg[r][i] holds cols chunk*32 + ((i+chunk)&7)*4 ..
#pragma unroll
    for (int r = 0; r < 4; ++r) {
      const int lr = rowgrp * 4 + r;
      const int grow = (lr >> 3) * HDIM + w * 8 + (lr & 7);
      const float4* wr = (const float4*)(whh + (size_t)grow * HDIM) + chunk * 8;
#pragma unroll
      for (int i = 0; i < 8; ++i) wreg[r][i] = wr[(i + chunk) & 7];
    }
    float my_gc = 0.f, my_gf = 0.f;
    if (wave == 0 && lane < 32) {
      const int R = (lane >> 3) * HDIM + w * 8 + (lane & 7);
      my_gc = gcv[R];
      my_gf = gfv[R];
    }

    bool fin = false;
    for (int t = 0; t < n && !fin; ++t) {
      const int s = sbase + t;
      // ---- poll tagged slots (4 units per lane, all 1024 covered by the WG) ----
      const u64* slot = a.hq + (size_t)(s & 1) * HDIM + tid * 4;
      u64 v0, v1, v2, v3;
      u32 t0, t1, t2, t3;
      int guard = 0;
      for (;;) {
        v0 = __hip_atomic_load(slot + 0, __ATOMIC_RELAXED, __HIP_MEMORY_SCOPE_AGENT);
        v1 = __hip_atomic_load(slot + 1, __ATOMIC_RELAXED, __HIP_MEMORY_SCOPE_AGENT);
        v2 = __hip_atomic_load(slot + 2, __ATOMIC_RELAXED, __HIP_MEMORY_SCOPE_AGENT);
        v3 = __hip_atomic_load(slot + 3, __ATOMIC_RELAXED, __HIP_MEMORY_SCOPE_AGENT);
        t0 = (u32)v0 & 0x7fffffffu; t1 = (u32)v1 & 0x7fffffffu;
        t2 = (u32)v2 & 0x7fffffffu; t3 = (u32)v3 & 0x7fffffffu;
        int ok = (t0 >= (u32)s) && (t1 >= (u32)s) && (t2 >= (u32)s) && (t3 >= (u32)s);
        if (__all(ok)) break;
        if (++guard > 4000000) break;  // anti-hang safety
      }
      int anyg = (t0 > (u32)s) || (t1 > (u32)s) || (t2 > (u32)s) || (t3 > (u32)s);
      int stall = (int)((((u32)v0) >> 31) & (((u32)v1) >> 31) &
                        (((u32)v2) >> 31) & (((u32)v3) >> 31));
      int wany = __any(anyg);
      int wall = __all(stall);
      if (lane == 0) lds_conv[wave] = (wall << 1) | wany;
      // publish the 4 polled h values into LDS
      float4 hv;
      hv.x = __uint_as_float((u32)(v0 >> 32));
      hv.y = __uint_as_float((u32)(v1 >> 32));
      hv.z = __uint_as_float((u32)(v2 >> 32));
      hv.w = __uint_as_float((u32)(v3 >> 32));
      ((float4*)lds_h)[tid] = hv;
      __syncthreads();  // B1
      const int c0 = lds_conv[0], c1 = lds_conv[1], c2 = lds_conv[2], c3 = lds_conv[3];
      const int convdec = ((c0 | c1 | c2 | c3) & 1) | (((c0 & c1 & c2 & c3) >> 1) & 1);

      if (convdec) {
        // State is within tolerance of the attractor (possibly tiny period-2):
        // fill remaining rows with the two parity phases.
        const int col = tid & 7;
        for (int tt = t + (tid >> 3); tt < n; tt += 32)
          __builtin_nontemporal_store(lds_h8[tt & 1][col],
                                      &hsout[(size_t)tt * HDIM + w * 8 + col]);
        if (wave == 0 && lane < 8) {
          float hlast = ((n - 1) & 1) ? hp1 : hp0;  // h(n-1)
          float clast = ((n - 1) & 1) ? cp1 : cp0;  // c(n-1)
          cstate = clast;
          u64 pub = (u64)(u32)(sbase + n) | ((u64)__float_as_uint(hlast) << 32);
          __hip_atomic_store(&a.hq[(size_t)((sbase + n) & 1) * HDIM + w * 8 + lane], pub,
                             __ATOMIC_RELAXED, __HIP_MEMORY_SCOPE_AGENT);
        }
        __syncthreads();
        fin = true;
        continue;
      }

      // ---- partial dot: 4 rows x 32 cols per lane, h from LDS (swizzled) ----
      float acc0 = 0.f, acc1 = 0.f, acc2 = 0.f, acc3 = 0.f;
      const float4* lh4 = (const float4*)lds_h + chunk * 8;
#pragma unroll
      for (int i = 0; i < 8; ++i) {
        float4 h4 = lh4[(i + chunk) & 7];
        acc0 += wreg[0][i].x * h4.x + wreg[0][i].y * h4.y + wreg[0][i].z * h4.z + wreg[0][i].w * h4.w;
        acc1 += wreg[1][i].x * h4.x + wreg[1][i].y * h4.y + wreg[1][i].z * h4.z + wreg[1][i].w * h4.w;
        acc2 += wreg[2][i].x * h4.x + wreg[2][i].y * h4.y + wreg[2][i].z * h4.z + wreg[2][i].w * h4.w;
        acc3 += wreg[3][i].x * h4.x + wreg[3][i].y * h4.y + wreg[3][i].z * h4.z + wreg[3][i].w * h4.w;
      }
      {
        float4 p; p.x = acc0; p.y = acc1; p.z = acc2; p.w = acc3;
        *(float4*)&lds_part[chunk * 36 + rowgrp * 4] = p;
      }
      __syncthreads();  // B2

      if (wave == 0) {
        float sum = 0.f;
        if (lane < 32) {
#pragma unroll
          for (int cc = 0; cc < 32; ++cc) sum += lds_part[cc * 36 + lane];
          sum += (t == tspecial) ? my_gf : my_gc;
        }
        const int j = lane & 7;
        float gi = __shfl(sum, j);
        float gf2 = __shfl(sum, 8 + j);
        float gg = __shfl(sum, 16 + j);
        float go = __shfl(sum, 24 + j);
        if (lane < 8) {
          float iv = 1.f / (1.f + expf(-gi));
          float fv = 1.f / (1.f + expf(-gf2));
          float gv = tanhf(gg);
          float ov = 1.f / (1.f + expf(-go));
          float cnew = fv * cstate + iv * gv;
          float hn = ov * tanhf(cnew);
          float h2 = (t & 1) ? hp1 : hp0;   // h(t-2)
          float c2v = (t & 1) ? cp1 : cp0;  // c(t-2)
          int stab = (fabsf(hn - h2) <= CONV_TOL) &&
                     (fabsf(cnew - c2v) <= CONV_TOL) &&
                     (t > tspecial + 2) && (t >= 32);
          if (t & 1) { hp1 = hn; cp1 = cnew; } else { hp0 = hn; cp0 = cnew; }
          cstate = cnew;
          lds_h8[t & 1][j] = hn;
          __builtin_nontemporal_store(hn, &hsout[(size_t)t * HDIM + w * 8 + j]);
          u32 tagw = (u32)(s + 1) | ((u32)stab << 31);
          u64 pub = (u64)tagw | ((u64)__float_as_uint(hn) << 32);
          __hip_atomic_store(&a.hq[(size_t)((s + 1) & 1) * HDIM + w * 8 + j], pub,
                             __ATOMIC_RELAXED, __HIP_MEMORY_SCOPE_AGENT);
        }
      }
      // waves 1..3 proceed straight to the next step's poll
    }
  }
}

// ---------------- lin1_w transpose: L1T[k][j] = lin1_w[j][k] ----------------
__global__ void transpose_kernel(const float* __restrict__ A, float* __restrict__ AT) {
  __shared__ float tile[32][33];
  int j0 = blockIdx.y * 32, k0 = blockIdx.x * 32;
  int tx = threadIdx.x & 31, ty = threadIdx.x >> 5;  // ty 0..7
  for (int r = ty; r < 32; r += 8) tile[r][tx] = A[(size_t)(j0 + r) * HDIM + k0 + tx];
  __syncthreads();
  for (int r = ty; r < 32; r += 8) AT[(size_t)(k0 + r) * HDIM + j0 + tx] = tile[tx][r];
}

// ---------------- beta[t] = sum_j u[j]*tanh( (O @ L1^T)[t][j] + b1[j] ) ----------------
#define TT 8
__global__ __launch_bounds__(256) void beta_kernel(const float* __restrict__ hsl,
                                                   const float* __restrict__ hsr,
                                                   const float* __restrict__ L1T,
                                                   const float* __restrict__ b1,
                                                   const float* __restrict__ u,
                                                   float* __restrict__ beta) {
  __shared__ float OT[128][9];
  __shared__ float red[4][TT];
  const int t0 = blockIdx.x * TT;
  const int tid = threadIdx.x;
  float acc[4][TT] = {};
  const float4 uv = ((const float4*)u)[tid];
  const float4 bv = ((const float4*)b1)[tid];

  for (int k0 = 0; k0 < HDIM; k0 += 128) {
    {  // stage O tile transposed: OT[k][t] = hsl*hsr
      int tt = tid >> 5, kk = tid & 31;
      const float4* l4 = (const float4*)(hsl + (size_t)(t0 + tt) * HDIM + k0);
      const float4* r4 = (const float4*)(hsr + (size_t)(t0 + tt) * HDIM + k0);
      float4 aa = l4[kk], bb = r4[kk];
      OT[kk * 4 + 0][tt] = aa.x * bb.x;
      OT[kk * 4 + 1][tt] = aa.y * bb.y;
      OT[kk * 4 + 2][tt] = aa.z * bb.z;
      OT[kk * 4 + 3][tt] = aa.w * bb.w;
    }
    __syncthreads();
    const float4* lp = (const float4*)L1T + (size_t)k0 * (HDIM / 4);
    for (int k = 0; k < 128; ++k) {
      float4 lv = lp[(size_t)k * (HDIM / 4) + tid];
      float ov[TT];
#pragma unroll
      for (int t = 0; t < TT; ++t) ov[t] = OT[k][t];
#pragma unroll
      for (int t = 0; t < TT; ++t) {
        acc[0][t] += lv.x * ov[t];
        acc[1][t] += lv.y * ov[t];
        acc[2][t] += lv.z * ov[t];
        acc[3][t] += lv.w * ov[t];
      }
    }
    __syncthreads();
  }
  float lc[TT];
#pragma unroll
  for (int t = 0; t < TT; ++t)
    lc[t] = uv.x * tanhf(acc[0][t] + bv.x) + uv.y * tanhf(acc[1][t] + bv.y) +
            uv.z * tanhf(acc[2][t] + bv.z) + uv.w * tanhf(acc[3][t] + bv.w);
  for (int off = 32; off; off >>= 1) {
#pragma unroll
    for (int t = 0; t < TT; ++t) lc[t] += __shfl_xor(lc[t], off);
  }
  if ((tid & 63) == 0) {
#pragma unroll
    for (int t = 0; t < TT; ++t) red[tid >> 6][t] = lc[t];
  }
  __syncthreads();
  if (tid < TT) beta[t0 + tid] = red[0][tid] + red[1][tid] + red[2][tid] + red[3][tid];
}

// ---------------- softmax over beta ----------------
__global__ void softmax_kernel(const float* __restrict__ beta, float* __restrict__ alfa, int n) {
  __shared__ float sm[8];
  int tid = threadIdx.x, lane = tid & 63, wv = tid >> 6;
  float m = -3.4e38f;
  for (int i = tid; i < n; i += 256) m = fmaxf(m, beta[i]);
  for (int off = 32; off; off >>= 1) m = fmaxf(m, __shfl_xor(m, off));
  if (lane == 0) sm[wv] = m;
  __syncthreads();
  float M = fmaxf(fmaxf(sm[0], sm[1]), fmaxf(sm[2], sm[3]));
  float s = 0.f;
  for (int i = tid; i < n; i += 256) s += expf(beta[i] - M);
  for (int off = 32; off; off >>= 1) s += __shfl_xor(s, off);
  if (lane == 0) sm[4 + wv] = s;
  __syncthreads();
  float inv = 1.f / (sm[4] + sm[5] + sm[6] + sm[7]);
  for (int i = tid; i < n; i += 256) alfa[i] = expf(beta[i] - M) * inv;
}

// ---------------- s[h] = sum_t alfa[t]*O[t][h] ----------------
__global__ void svec_kernel(const float* __restrict__ alfa, const float* __restrict__ hsl,
                            const float* __restrict__ hsr, float* __restrict__ svec, int n) {
  __shared__ float red[4][64];
  int h = blockIdx.x * 64 + (threadIdx.x & 63);
  int ts = threadIdx.x >> 6;
  float s = 0.f;
  for (int t = ts; t < n; t += 4)
    s += alfa[t] * hsl[(size_t)t * HDIM + h] * hsr[(size_t)t * HDIM + h];
  red[ts][threadIdx.x & 63] = s;
  __syncthreads();
  if (threadIdx.x < 64)
    svec[blockIdx.x * 64 + threadIdx.x] =
        red[0][threadIdx.x] + red[1][threadIdx.x] + red[2][threadIdx.x] + red[3][threadIdx.x];
}

// ---------------- out[r] = lin2_w[r] . s + lin2_b[r] ----------------
__global__ void final_kernel(const float* __restrict__ svec, const float* __restrict__ l2w,
                             const float* __restrict__ l2b, float* __restrict__ out) {
  int r = threadIdx.x >> 6, lane = threadIdx.x & 63;
  float s = 0.f;
  for (int k = lane; k < HDIM; k += 64) s += l2w[(size_t)r * HDIM + k] * svec[k];
  for (int off = 32; off; off >>= 1) s += __shfl_xor(s, off);
  if (lane == 0) out[r] = s + l2b[r];
}

extern "C" void kernel_launch(void* const* d_in, const int* in_sizes, int n_in,
                              void* d_out, int out_size, void* d_ws, size_t ws_size,
                              hipStream_t stream) {
  const int* x = (const int*)d_in[0];
  const int* tstart = (const int*)d_in[1];
  const int* tend = (const int*)d_in[2];
  const float* emb = (const float*)d_in[3];
  const float* wih_l = (const float*)d_in[4];
  const float* whh_l = (const float*)d_in[5];
  const float* bih_l = (const float*)d_in[6];
  const float* bhh_l = (const float*)d_in[7];
  const float* wih_r = (const float*)d_in[8];
  const float* whh_r = (const float*)d_in[9];
  const float* bih_r = (const float*)d_in[10];
  const float* bhh_r = (const float*)d_in[11];
  const float* l1w = (const float*)d_in[12];
  const float* l1b = (const float*)d_in[13];
  const float* u = (const float*)d_in[14];
  const float* l2w = (const float*)d_in[15];
  const float* l2b = (const float*)d_in[16];
  const int n = in_sizes[0];  // 2048
  (void)n_in; (void)out_size; (void)ws_size;

  float* ws = (float*)d_ws;
  float* target = ws;                     // 1024
  float* seqfl = ws + 1024;               // 1024
  float* seqfr = ws + 2048;               // 1024
  float* glc = ws + 3072;                 // 4096
  float* glf = glc + 4096;                // 4096
  float* grc = glf + 4096;                // 4096
  float* grf = grc + 4096;                // 4096
  u64* hq = (u64*)(grf + 4096);           // 2*1024 u64 (8B aligned: offset is 8*4096B)
  float* hsl = (float*)(hq + 2 * HDIM);   // n*1024
  float* hsr = hsl + (size_t)n * HDIM;    // n*1024
  float* L1T = hsr + (size_t)n * HDIM;    // 1024*1024
  float* beta = L1T + (size_t)HDIM * HDIM;  // n
  float* alfa = beta + n;                 // n
  float* svec = alfa + n;                 // 1024

  setup_kernel<<<1, 1024, 0, stream>>>(x, tstart, tend, emb, target, seqfl, seqfr, hq, n);
  gateconst_kernel<<<dim3(1024, 2), 256, 0, stream>>>(wih_l, bih_l, bhh_l, wih_r, bih_r, bhh_r,
                                                      target, seqfl, seqfr, glc, glf, grc, grf);
  RecArgs ra;
  ra.whh_l = whh_l; ra.whh_r = whh_r;
  ra.glc = glc; ra.glf = glf; ra.grc = grc; ra.grf = grf;
  ra.hq = hq; ra.hsl = hsl; ra.hsr = hsr;
  ra.pstart = tstart; ra.pend = tend; ra.n = n;
  void* kargs[] = {(void*)&ra};
  hipLaunchCooperativeKernel((const void*)rec_kernel, dim3(NWG), dim3(TPB), kargs, 0, stream);

  transpose_kernel<<<dim3(32, 32), 256, 0, stream>>>(l1w, L1T);
  beta_kernel<<<dim3(n / TT), 256, 0, stream>>>(hsl, hsr, L1T, l1b, u, beta);
  softmax_kernel<<<1, 256, 0, stream>>>(beta, alfa, n);
  svec_kernel<<<16, 256, 0, stream>>>(alfa, hsl, hsr, svec, n);
  final_kernel<<<1, 192, 0, stream>>>(svec, l2w, l2b, (float*)d_out);
}

// Round 5
// 1118.881 us; speedup vs baseline: 33.2697x; 1.1314x over previous
//
#include <hip/hip_runtime.h>
#include <math.h>

#define HDIM 1024
#define NWG 128
#define TPB 256
#define CONV_TOL 1.0e-7f

typedef unsigned long long u64;
typedef unsigned int u32;

struct RecArgs {
  const float* whh_l; const float* whh_r;
  const float* glc; const float* glf; const float* grc; const float* grf;
  u64* hq;            // [2][HDIM] tagged slots: low32 = tag | stable<<31, high32 = f32 bits
  float* hsl;         // [n][HDIM]
  float* hsr;         // [n][HDIM]
  const int* pstart; const int* pend;
  int n;
};

// ---------------- setup: target vector, special rows, tagged-state init, accum zeroing ----------------
__global__ void setup_kernel(const int* __restrict__ x, const int* ts, const int* te,
                             const float* __restrict__ emb,
                             float* target, float* seqfl, float* seqfr,
                             u64* hq, float* beta, float* svec, int n) {
  int e = threadIdx.x;  // 0..1023
  int start = ts[0], end = te[0];
  int first_l = (start > 0) ? 0 : (end + 1);
  int first_r = (end < n - 1) ? (n - 1) : (start - 1);
  int fl = min(max(first_l, 0), n - 1);
  int fr = min(max(first_r, 0), n - 1);
  float sum = 0.f;
  for (int p = start; p <= end; ++p) sum += emb[(size_t)x[p] * HDIM + e];
  target[e] = sum / (float)(end - start + 1);
  seqfl[e] = emb[(size_t)x[fl] * HDIM + e];
  seqfr[e] = emb[(size_t)x[fr] * HDIM + e];
  // tag=0 (h input for step 0), value = 0.0f, stable=0 — both parities
  hq[e] = 0ull;
  hq[HDIM + e] = 0ull;
  for (int i = e; i < n; i += 1024) beta[i] = 0.f;
  svec[e] = 0.f;
}

// ---------------- gate-constant vectors: w_ih@v + b_ih + b_hh ----------------
__global__ __launch_bounds__(256) void gateconst_kernel(
    const float* __restrict__ wih_l, const float* bih_l, const float* bhh_l,
    const float* __restrict__ wih_r, const float* bih_r, const float* bhh_r,
    const float* __restrict__ target, const float* __restrict__ seqfl,
    const float* __restrict__ seqfr,
    float* glc, float* glf, float* grc, float* grf) {
  int side = blockIdx.y;
  const float* wih = side ? wih_r : wih_l;
  const float* bih = side ? bih_r : bih_l;
  const float* bhh = side ? bhh_r : bhh_l;
  const float* sf = side ? seqfr : seqfl;
  float* outc = side ? grc : glc;
  float* outf = side ? grf : glf;
  int wv = threadIdx.x >> 6, lane = threadIdx.x & 63;
  int r = blockIdx.x * 4 + wv;  // 0..4095
  const float4* wrow = (const float4*)(wih + (size_t)r * HDIM);
  const float4* tg4 = (const float4*)target;
  const float4* sf4 = (const float4*)sf;
  float dc = 0.f, df = 0.f;
#pragma unroll
  for (int k = 0; k < 4; ++k) {
    float4 w4 = wrow[lane + 64 * k];
    float4 t4 = tg4[lane + 64 * k];
    float4 s4 = sf4[lane + 64 * k];
    dc += w4.x * t4.x + w4.y * t4.y + w4.z * t4.z + w4.w * t4.w;
    df += w4.x * s4.x + w4.y * s4.y + w4.z * s4.z + w4.w * s4.w;
  }
  for (int off = 32; off; off >>= 1) {
    dc += __shfl_xor(dc, off);
    df += __shfl_xor(df, off);
  }
  if (lane == 0) {
    float bb = bih[r] + bhh[r];
    outc[r] = dc + bb;
    outf[r] = df + bb;
  }
}

// ---------------- persistent cooperative recurrence (unchanged from R4) ----------------
__global__ __launch_bounds__(TPB, 1) void rec_kernel(RecArgs a) {
  const int w = blockIdx.x;
  const int tid = threadIdx.x;
  const int wave = tid >> 6;
  const int lane = tid & 63;
  const int chunk = tid & 31;    // 32-col chunk of the k dimension
  const int rowgrp = tid >> 5;   // 0..7 -> local rows rowgrp*4..+3
  const int n = a.n;

  __shared__ float lds_h[HDIM];
  __shared__ float lds_part[32 * 36];  // [chunk][row] pitch 36 floats (16B-aligned rows)
  __shared__ float lds_h8[2][8];       // [local parity][unit]
  __shared__ int lds_conv[4];

  const int start = a.pstart[0];
  const int end = a.pend[0];
  const int first_l = (start > 0) ? 0 : (end + 1);
  const int first_r = (end < n - 1) ? (n - 1) : (start - 1);

  float4 wreg[4][8];  // constant-indexed only => guaranteed VGPR residency
  float cstate = 0.f;
  float hp0 = 0.f, hp1 = 0.f, cp0 = 0.f, cp1 = 0.f;  // parity history

  for (int pass = 0; pass < 2; ++pass) {
    const float* whh = pass ? a.whh_r : a.whh_l;
    const float* gcv = pass ? a.grc : a.glc;
    const float* gfv = pass ? a.grf : a.glf;
    float* hsout = pass ? a.hsr : a.hsl;
    const int tspecial = pass ? (n - 1 - first_r) : first_l;
    const int sbase = pass * n;

#pragma unroll
    for (int r = 0; r < 4; ++r) {
      const int lr = rowgrp * 4 + r;
      const int grow = (lr >> 3) * HDIM + w * 8 + (lr & 7);
      const float4* wr = (const float4*)(whh + (size_t)grow * HDIM) + chunk * 8;
#pragma unroll
      for (int i = 0; i < 8; ++i) wreg[r][i] = wr[(i + chunk) & 7];
    }
    float my_gc = 0.f, my_gf = 0.f;
    if (wave == 0 && lane < 32) {
      const int R = (lane >> 3) * HDIM + w * 8 + (lane & 7);
      my_gc = gcv[R];
      my_gf = gfv[R];
    }

    bool fin = false;
    for (int t = 0; t < n && !fin; ++t) {
      const int s = sbase + t;
      const u64* slot = a.hq + (size_t)(s & 1) * HDIM + tid * 4;
      u64 v0, v1, v2, v3;
      u32 t0, t1, t2, t3;
      int guard = 0;
      for (;;) {
        v0 = __hip_atomic_load(slot + 0, __ATOMIC_RELAXED, __HIP_MEMORY_SCOPE_AGENT);
        v1 = __hip_atomic_load(slot + 1, __ATOMIC_RELAXED, __HIP_MEMORY_SCOPE_AGENT);
        v2 = __hip_atomic_load(slot + 2, __ATOMIC_RELAXED, __HIP_MEMORY_SCOPE_AGENT);
        v3 = __hip_atomic_load(slot + 3, __ATOMIC_RELAXED, __HIP_MEMORY_SCOPE_AGENT);
        t0 = (u32)v0 & 0x7fffffffu; t1 = (u32)v1 & 0x7fffffffu;
        t2 = (u32)v2 & 0x7fffffffu; t3 = (u32)v3 & 0x7fffffffu;
        int ok = (t0 >= (u32)s) && (t1 >= (u32)s) && (t2 >= (u32)s) && (t3 >= (u32)s);
        if (__all(ok)) break;
        if (++guard > 4000000) break;  // anti-hang safety
      }
      int anyg = (t0 > (u32)s) || (t1 > (u32)s) || (t2 > (u32)s) || (t3 > (u32)s);
      int stall = (int)((((u32)v0) >> 31) & (((u32)v1) >> 31) &
                        (((u32)v2) >> 31) & (((u32)v3) >> 31));
      int wany = __any(anyg);
      int wall = __all(stall);
      if (lane == 0) lds_conv[wave] = (wall << 1) | wany;
      float4 hv;
      hv.x = __uint_as_float((u32)(v0 >> 32));
      hv.y = __uint_as_float((u32)(v1 >> 32));
      hv.z = __uint_as_float((u32)(v2 >> 32));
      hv.w = __uint_as_float((u32)(v3 >> 32));
      ((float4*)lds_h)[tid] = hv;
      __syncthreads();  // B1
      const int c0 = lds_conv[0], c1 = lds_conv[1], c2 = lds_conv[2], c3 = lds_conv[3];
      const int convdec = ((c0 | c1 | c2 | c3) & 1) | (((c0 & c1 & c2 & c3) >> 1) & 1);

      if (convdec) {
        const int col = tid & 7;
        for (int tt = t + (tid >> 3); tt < n; tt += 32)
          __builtin_nontemporal_store(lds_h8[tt & 1][col],
                                      &hsout[(size_t)tt * HDIM + w * 8 + col]);
        if (wave == 0 && lane < 8) {
          float hlast = ((n - 1) & 1) ? hp1 : hp0;  // h(n-1)
          float clast = ((n - 1) & 1) ? cp1 : cp0;  // c(n-1)
          cstate = clast;
          u64 pub = (u64)(u32)(sbase + n) | ((u64)__float_as_uint(hlast) << 32);
          __hip_atomic_store(&a.hq[(size_t)((sbase + n) & 1) * HDIM + w * 8 + lane], pub,
                             __ATOMIC_RELAXED, __HIP_MEMORY_SCOPE_AGENT);
        }
        __syncthreads();
        fin = true;
        continue;
      }

      float acc0 = 0.f, acc1 = 0.f, acc2 = 0.f, acc3 = 0.f;
      const float4* lh4 = (const float4*)lds_h + chunk * 8;
#pragma unroll
      for (int i = 0; i < 8; ++i) {
        float4 h4 = lh4[(i + chunk) & 7];
        acc0 += wreg[0][i].x * h4.x + wreg[0][i].y * h4.y + wreg[0][i].z * h4.z + wreg[0][i].w * h4.w;
        acc1 += wreg[1][i].x * h4.x + wreg[1][i].y * h4.y + wreg[1][i].z * h4.z + wreg[1][i].w * h4.w;
        acc2 += wreg[2][i].x * h4.x + wreg[2][i].y * h4.y + wreg[2][i].z * h4.z + wreg[2][i].w * h4.w;
        acc3 += wreg[3][i].x * h4.x + wreg[3][i].y * h4.y + wreg[3][i].z * h4.z + wreg[3][i].w * h4.w;
      }
      {
        float4 p; p.x = acc0; p.y = acc1; p.z = acc2; p.w = acc3;
        *(float4*)&lds_part[chunk * 36 + rowgrp * 4] = p;
      }
      __syncthreads();  // B2

      if (wave == 0) {
        float sum = 0.f;
        if (lane < 32) {
#pragma unroll
          for (int cc = 0; cc < 32; ++cc) sum += lds_part[cc * 36 + lane];
          sum += (t == tspecial) ? my_gf : my_gc;
        }
        const int j = lane & 7;
        float gi = __shfl(sum, j);
        float gf2 = __shfl(sum, 8 + j);
        float gg = __shfl(sum, 16 + j);
        float go = __shfl(sum, 24 + j);
        if (lane < 8) {
          float iv = 1.f / (1.f + expf(-gi));
          float fv = 1.f / (1.f + expf(-gf2));
          float gv = tanhf(gg);
          float ov = 1.f / (1.f + expf(-go));
          float cnew = fv * cstate + iv * gv;
          float hn = ov * tanhf(cnew);
          float h2 = (t & 1) ? hp1 : hp0;   // h(t-2)
          float c2v = (t & 1) ? cp1 : cp0;  // c(t-2)
          int stab = (fabsf(hn - h2) <= CONV_TOL) &&
                     (fabsf(cnew - c2v) <= CONV_TOL) &&
                     (t > tspecial + 2) && (t >= 32);
          if (t & 1) { hp1 = hn; cp1 = cnew; } else { hp0 = hn; cp0 = cnew; }
          cstate = cnew;
          lds_h8[t & 1][j] = hn;
          __builtin_nontemporal_store(hn, &hsout[(size_t)t * HDIM + w * 8 + j]);
          u32 tagw = (u32)(s + 1) | ((u32)stab << 31);
          u64 pub = (u64)tagw | ((u64)__float_as_uint(hn) << 32);
          __hip_atomic_store(&a.hq[(size_t)((s + 1) & 1) * HDIM + w * 8 + j], pub,
                             __ATOMIC_RELAXED, __HIP_MEMORY_SCOPE_AGENT);
        }
      }
    }
  }
}

// ---------------- lin1_w transpose: L1T[k][j] = lin1_w[j][k] ----------------
__global__ void transpose_kernel(const float* __restrict__ A, float* __restrict__ AT) {
  __shared__ float tile[32][33];
  int j0 = blockIdx.y * 32, k0 = blockIdx.x * 32;
  int tx = threadIdx.x & 31, ty = threadIdx.x >> 5;  // ty 0..7
  for (int r = ty; r < 32; r += 8) tile[r][tx] = A[(size_t)(j0 + r) * HDIM + k0 + tx];
  __syncthreads();
  for (int r = ty; r < 32; r += 8) AT[(size_t)(k0 + r) * HDIM + j0 + tx] = tile[tx][r];
}

// ---------------- beta via tiled GEMM: Pre = (hsl.*hsr) @ L1T, fused tanh/u epilogue ----------------
// Tile: 128 t x 64 j, K-panels of 32. Grid (n/128, HDIM/64). Each thread: 8t x 4j micro-tile.
__global__ __launch_bounds__(256) void beta_gemm_kernel(
    const float* __restrict__ hsl, const float* __restrict__ hsr,
    const float* __restrict__ L1T, const float* __restrict__ b1,
    const float* __restrict__ u, float* __restrict__ beta) {
  __shared__ float As[32][128];
  __shared__ float Bs[32][64];
  const int tid = threadIdx.x;
  const int t0 = blockIdx.x * 128;
  const int j0 = blockIdx.y * 64;
  const int tm = tid >> 4;       // 0..15 -> rows t0 + tm*8 .. +7
  const int tj = tid & 15;       // 0..15 -> cols j0 + tj*4 .. +3
  const int sr = tid >> 1;       // A-staging row 0..127
  const int sc = (tid & 1) * 4;  // A-staging float4 col base

  float acc[8][4] = {};
  const float4 uv = *(const float4*)(u + j0 + tj * 4);
  const float4 bv = *(const float4*)(b1 + j0 + tj * 4);

  for (int k0 = 0; k0 < HDIM; k0 += 32) {
    {  // stage A = hsl.*hsr, transposed to [k][m]; one 128B line per row per panel
      const float4* l4 = (const float4*)(hsl + (size_t)(t0 + sr) * HDIM + k0);
      const float4* r4 = (const float4*)(hsr + (size_t)(t0 + sr) * HDIM + k0);
#pragma unroll
      for (int i = 0; i < 4; ++i) {
        float4 av = l4[sc + i], ov = r4[sc + i];
        As[(sc + i) * 4 + 0][sr] = av.x * ov.x;
        As[(sc + i) * 4 + 1][sr] = av.y * ov.y;
        As[(sc + i) * 4 + 2][sr] = av.z * ov.z;
        As[(sc + i) * 4 + 3][sr] = av.w * ov.w;
      }
    }
    {  // stage B: Bs[kk][jj] = L1T[k0+kk][j0+jj]
#pragma unroll
      for (int i = 0; i < 2; ++i) {
        int idx = tid + i * 256;  // 0..511
        int kk = idx >> 4;        // 0..31
        int jb = idx & 15;        // 0..15
        *(float4*)&Bs[kk][jb * 4] =
            *(const float4*)(L1T + (size_t)(k0 + kk) * HDIM + j0 + jb * 4);
      }
    }
    __syncthreads();
#pragma unroll
    for (int kk = 0; kk < 32; ++kk) {
      float4 a0 = *(float4*)&As[kk][tm * 8];
      float4 a1 = *(float4*)&As[kk][tm * 8 + 4];
      float4 b = *(float4*)&Bs[kk][tj * 4];
      float ar[8] = {a0.x, a0.y, a0.z, a0.w, a1.x, a1.y, a1.z, a1.w};
      float bc[4] = {b.x, b.y, b.z, b.w};
#pragma unroll
      for (int r = 0; r < 8; ++r)
#pragma unroll
        for (int c = 0; c < 4; ++c) acc[r][c] += ar[r] * bc[c];
    }
    __syncthreads();
  }
  // epilogue: pb[r] = sum_c u[j]*tanh(acc + b1[j]); reduce over the 16 tj lanes; atomicAdd
  float ures[4] = {uv.x, uv.y, uv.z, uv.w};
  float bres[4] = {bv.x, bv.y, bv.z, bv.w};
#pragma unroll
  for (int r = 0; r < 8; ++r) {
    float pb = ures[0] * tanhf(acc[r][0] + bres[0]) + ures[1] * tanhf(acc[r][1] + bres[1]) +
               ures[2] * tanhf(acc[r][2] + bres[2]) + ures[3] * tanhf(acc[r][3] + bres[3]);
#pragma unroll
    for (int off = 1; off < 16; off <<= 1) pb += __shfl_xor(pb, off);
    if (tj == 0) atomicAdd(&beta[t0 + tm * 8 + r], pb);
  }
}

// ---------------- softmax over beta ----------------
__global__ void softmax_kernel(const float* __restrict__ beta, float* __restrict__ alfa, int n) {
  __shared__ float sm[8];
  int tid = threadIdx.x, lane = tid & 63, wv = tid >> 6;
  float m = -3.4e38f;
  for (int i = tid; i < n; i += 256) m = fmaxf(m, beta[i]);
  for (int off = 32; off; off >>= 1) m = fmaxf(m, __shfl_xor(m, off));
  if (lane == 0) sm[wv] = m;
  __syncthreads();
  float M = fmaxf(fmaxf(sm[0], sm[1]), fmaxf(sm[2], sm[3]));
  float s = 0.f;
  for (int i = tid; i < n; i += 256) s += expf(beta[i] - M);
  for (int off = 32; off; off >>= 1) s += __shfl_xor(s, off);
  if (lane == 0) sm[4 + wv] = s;
  __syncthreads();
  float inv = 1.f / (sm[4] + sm[5] + sm[6] + sm[7]);
  for (int i = tid; i < n; i += 256) alfa[i] = expf(beta[i] - M) * inv;
}

// ---------------- s[h] += sum_{t in chunk} alfa[t]*O[t][h] ----------------
__global__ void svec_kernel(const float* __restrict__ alfa, const float* __restrict__ hsl,
                            const float* __restrict__ hsr, float* __restrict__ svec, int n) {
  __shared__ float red[4][64];
  const int h = blockIdx.x * 64 + (threadIdx.x & 63);
  const int ts = threadIdx.x >> 6;
  const int tlen = n / gridDim.y;
  const int tbeg = blockIdx.y * tlen;
  float s = 0.f;
  for (int t = tbeg + ts; t < tbeg + tlen; t += 4)
    s += alfa[t] * hsl[(size_t)t * HDIM + h] * hsr[(size_t)t * HDIM + h];
  red[ts][threadIdx.x & 63] = s;
  __syncthreads();
  if (threadIdx.x < 64) {
    float tot = red[0][threadIdx.x] + red[1][threadIdx.x] +
                red[2][threadIdx.x] + red[3][threadIdx.x];
    atomicAdd(&svec[blockIdx.x * 64 + threadIdx.x], tot);
  }
}

// ---------------- out[r] = lin2_w[r] . s + lin2_b[r] ----------------
__global__ void final_kernel(const float* __restrict__ svec, const float* __restrict__ l2w,
                             const float* __restrict__ l2b, float* __restrict__ out) {
  int r = threadIdx.x >> 6, lane = threadIdx.x & 63;
  float s = 0.f;
  for (int k = lane; k < HDIM; k += 64) s += l2w[(size_t)r * HDIM + k] * svec[k];
  for (int off = 32; off; off >>= 1) s += __shfl_xor(s, off);
  if (lane == 0) out[r] = s + l2b[r];
}

extern "C" void kernel_launch(void* const* d_in, const int* in_sizes, int n_in,
                              void* d_out, int out_size, void* d_ws, size_t ws_size,
                              hipStream_t stream) {
  const int* x = (const int*)d_in[0];
  const int* tstart = (const int*)d_in[1];
  const int* tend = (const int*)d_in[2];
  const float* emb = (const float*)d_in[3];
  const float* wih_l = (const float*)d_in[4];
  const float* whh_l = (const float*)d_in[5];
  const float* bih_l = (const float*)d_in[6];
  const float* bhh_l = (const float*)d_in[7];
  const float* wih_r = (const float*)d_in[8];
  const float* whh_r = (const float*)d_in[9];
  const float* bih_r = (const float*)d_in[10];
  const float* bhh_r = (const float*)d_in[11];
  const float* l1w = (const float*)d_in[12];
  const float* l1b = (const float*)d_in[13];
  const float* u = (const float*)d_in[14];
  const float* l2w = (const float*)d_in[15];
  const float* l2b = (const float*)d_in[16];
  const int n = in_sizes[0];  // 2048
  (void)n_in; (void)out_size; (void)ws_size;

  float* ws = (float*)d_ws;
  float* target = ws;                     // 1024
  float* seqfl = ws + 1024;               // 1024
  float* seqfr = ws + 2048;               // 1024
  float* glc = ws + 3072;                 // 4096
  float* glf = glc + 4096;                // 4096
  float* grc = glf + 4096;                // 4096
  float* grf = grc + 4096;                // 4096
  u64* hq = (u64*)(grf + 4096);           // 2*1024 u64 (8B aligned)
  float* hsl = (float*)(hq + 2 * HDIM);   // n*1024
  float* hsr = hsl + (size_t)n * HDIM;    // n*1024
  float* L1T = hsr + (size_t)n * HDIM;    // 1024*1024
  float* beta = L1T + (size_t)HDIM * HDIM;  // n
  float* alfa = beta + n;                 // n
  float* svec = alfa + n;                 // 1024

  setup_kernel<<<1, 1024, 0, stream>>>(x, tstart, tend, emb, target, seqfl, seqfr, hq,
                                       beta, svec, n);
  gateconst_kernel<<<dim3(1024, 2), 256, 0, stream>>>(wih_l, bih_l, bhh_l, wih_r, bih_r, bhh_r,
                                                      target, seqfl, seqfr, glc, glf, grc, grf);
  RecArgs ra;
  ra.whh_l = whh_l; ra.whh_r = whh_r;
  ra.glc = glc; ra.glf = glf; ra.grc = grc; ra.grf = grf;
  ra.hq = hq; ra.hsl = hsl; ra.hsr = hsr;
  ra.pstart = tstart; ra.pend = tend; ra.n = n;
  void* kargs[] = {(void*)&ra};
  hipLaunchCooperativeKernel((const void*)rec_kernel, dim3(NWG), dim3(TPB), kargs, 0, stream);

  transpose_kernel<<<dim3(32, 32), 256, 0, stream>>>(l1w, L1T);
  beta_gemm_kernel<<<dim3(n / 128, HDIM / 64), 256, 0, stream>>>(hsl, hsr, L1T, l1b, u, beta);
  softmax_kernel<<<1, 256, 0, stream>>>(beta, alfa, n);
  svec_kernel<<<dim3(16, 8), 256, 0, stream>>>(alfa, hsl, hsr, svec, n);
  final_kernel<<<1, 192, 0, stream>>>(svec, l2w, l2b, (float*)d_out);
}

// Round 6
// 887.637 us; speedup vs baseline: 41.9371x; 1.2605x over previous
//
#include <hip/hip_runtime.h>
#include <math.h>

#define HDIM 1024
#define NWG 128
#define TPB 256
#define CONV_TOL 1.0e-5f

typedef unsigned long long u64;
typedef unsigned int u32;

struct RecArgs {
  const float* whh_l; const float* whh_r;
  const float* glc; const float* glf; const float* grc; const float* grf;
  u64* hq;            // [2][HDIM] tagged slots: low32 = tag | stable<<31, high32 = f32 bits
  float* hsl;         // [n][HDIM]
  float* hsr;         // [n][HDIM]
  const int* pstart; const int* pend;
  int n;
};

// ---------------- setup: target vector, special rows, tagged-state init, accum zeroing ----------------
__global__ void setup_kernel(const int* __restrict__ x, const int* ts, const int* te,
                             const float* __restrict__ emb,
                             float* target, float* seqfl, float* seqfr,
                             u64* hq, float* beta, float* svec, int n) {
  int e = threadIdx.x;  // 0..1023
  int start = ts[0], end = te[0];
  int first_l = (start > 0) ? 0 : (end + 1);
  int first_r = (end < n - 1) ? (n - 1) : (start - 1);
  int fl = min(max(first_l, 0), n - 1);
  int fr = min(max(first_r, 0), n - 1);
  float sum = 0.f;
  for (int p = start; p <= end; ++p) sum += emb[(size_t)x[p] * HDIM + e];
  target[e] = sum / (float)(end - start + 1);
  seqfl[e] = emb[(size_t)x[fl] * HDIM + e];
  seqfr[e] = emb[(size_t)x[fr] * HDIM + e];
  // tag=0 (h input for step 0), value = 0.0f, stable=0 — both parities
  hq[e] = 0ull;
  hq[HDIM + e] = 0ull;
  for (int i = e; i < n; i += 1024) beta[i] = 0.f;
  svec[e] = 0.f;
}

// ---------------- gate-constant vectors: w_ih@v + b_ih + b_hh ----------------
__global__ __launch_bounds__(256) void gateconst_kernel(
    const float* __restrict__ wih_l, const float* bih_l, const float* bhh_l,
    const float* __restrict__ wih_r, const float* bih_r, const float* bhh_r,
    const float* __restrict__ target, const float* __restrict__ seqfl,
    const float* __restrict__ seqfr,
    float* glc, float* glf, float* grc, float* grf) {
  int side = blockIdx.y;
  const float* wih = side ? wih_r : wih_l;
  const float* bih = side ? bih_r : bih_l;
  const float* bhh = side ? bhh_r : bhh_l;
  const float* sf = side ? seqfr : seqfl;
  float* outc = side ? grc : glc;
  float* outf = side ? grf : glf;
  int wv = threadIdx.x >> 6, lane = threadIdx.x & 63;
  int r = blockIdx.x * 4 + wv;  // 0..4095
  const float4* wrow = (const float4*)(wih + (size_t)r * HDIM);
  const float4* tg4 = (const float4*)target;
  const float4* sf4 = (const float4*)sf;
  float dc = 0.f, df = 0.f;
#pragma unroll
  for (int k = 0; k < 4; ++k) {
    float4 w4 = wrow[lane + 64 * k];
    float4 t4 = tg4[lane + 64 * k];
    float4 s4 = sf4[lane + 64 * k];
    dc += w4.x * t4.x + w4.y * t4.y + w4.z * t4.z + w4.w * t4.w;
    df += w4.x * s4.x + w4.y * s4.y + w4.z * s4.z + w4.w * s4.w;
  }
  for (int off = 32; off; off >>= 1) {
    dc += __shfl_xor(dc, off);
    df += __shfl_xor(df, off);
  }
  if (lane == 0) {
    float bb = bih[r] + bhh[r];
    outc[r] = dc + bb;
    outf[r] = df + bb;
  }
}

// ---------------- persistent cooperative recurrence (structure unchanged; tol raised) ----------------
__global__ __launch_bounds__(TPB, 1) void rec_kernel(RecArgs a) {
  const int w = blockIdx.x;
  const int tid = threadIdx.x;
  const int wave = tid >> 6;
  const int lane = tid & 63;
  const int chunk = tid & 31;    // 32-col chunk of the k dimension
  const int rowgrp = tid >> 5;   // 0..7 -> local rows rowgrp*4..+3
  const int n = a.n;

  __shared__ float lds_h[HDIM];
  __shared__ float lds_part[32 * 36];  // [chunk][row] pitch 36 floats (16B-aligned rows)
  __shared__ float lds_h8[2][8];       // [local parity][unit]
  __shared__ int lds_conv[4];

  const int start = a.pstart[0];
  const int end = a.pend[0];
  const int first_l = (start > 0) ? 0 : (end + 1);
  const int first_r = (end < n - 1) ? (n - 1) : (start - 1);

  float4 wreg[4][8];  // constant-indexed only => guaranteed VGPR residency
  float cstate = 0.f;
  float hp0 = 0.f, hp1 = 0.f, cp0 = 0.f, cp1 = 0.f;  // parity history

  for (int pass = 0; pass < 2; ++pass) {
    const float* whh = pass ? a.whh_r : a.whh_l;
    const float* gcv = pass ? a.grc : a.glc;
    const float* gfv = pass ? a.grf : a.glf;
    float* hsout = pass ? a.hsr : a.hsl;
    const int tspecial = pass ? (n - 1 - first_r) : first_l;
    const int sbase = pass * n;

#pragma unroll
    for (int r = 0; r < 4; ++r) {
      const int lr = rowgrp * 4 + r;
      const int grow = (lr >> 3) * HDIM + w * 8 + (lr & 7);
      const float4* wr = (const float4*)(whh + (size_t)grow * HDIM) + chunk * 8;
#pragma unroll
      for (int i = 0; i < 8; ++i) wreg[r][i] = wr[(i + chunk) & 7];
    }
    float my_gc = 0.f, my_gf = 0.f;
    if (wave == 0 && lane < 32) {
      const int R = (lane >> 3) * HDIM + w * 8 + (lane & 7);
      my_gc = gcv[R];
      my_gf = gfv[R];
    }

    bool fin = false;
    for (int t = 0; t < n && !fin; ++t) {
      const int s = sbase + t;
      const u64* slot = a.hq + (size_t)(s & 1) * HDIM + tid * 4;
      u64 v0, v1, v2, v3;
      u32 t0, t1, t2, t3;
      int guard = 0;
      for (;;) {
        v0 = __hip_atomic_load(slot + 0, __ATOMIC_RELAXED, __HIP_MEMORY_SCOPE_AGENT);
        v1 = __hip_atomic_load(slot + 1, __ATOMIC_RELAXED, __HIP_MEMORY_SCOPE_AGENT);
        v2 = __hip_atomic_load(slot + 2, __ATOMIC_RELAXED, __HIP_MEMORY_SCOPE_AGENT);
        v3 = __hip_atomic_load(slot + 3, __ATOMIC_RELAXED, __HIP_MEMORY_SCOPE_AGENT);
        t0 = (u32)v0 & 0x7fffffffu; t1 = (u32)v1 & 0x7fffffffu;
        t2 = (u32)v2 & 0x7fffffffu; t3 = (u32)v3 & 0x7fffffffu;
        int ok = (t0 >= (u32)s) && (t1 >= (u32)s) && (t2 >= (u32)s) && (t3 >= (u32)s);
        if (__all(ok)) break;
        if (++guard > 4000000) break;  // anti-hang safety
      }
      int anyg = (t0 > (u32)s) || (t1 > (u32)s) || (t2 > (u32)s) || (t3 > (u32)s);
      int stall = (int)((((u32)v0) >> 31) & (((u32)v1) >> 31) &
                        (((u32)v2) >> 31) & (((u32)v3) >> 31));
      int wany = __any(anyg);
      int wall = __all(stall);
      if (lane == 0) lds_conv[wave] = (wall << 1) | wany;
      float4 hv;
      hv.x = __uint_as_float((u32)(v0 >> 32));
      hv.y = __uint_as_float((u32)(v1 >> 32));
      hv.z = __uint_as_float((u32)(v2 >> 32));
      hv.w = __uint_as_float((u32)(v3 >> 32));
      ((float4*)lds_h)[tid] = hv;
      __syncthreads();  // B1
      const int c0 = lds_conv[0], c1 = lds_conv[1], c2 = lds_conv[2], c3 = lds_conv[3];
      const int convdec = ((c0 | c1 | c2 | c3) & 1) | (((c0 & c1 & c2 & c3) >> 1) & 1);

      if (convdec) {
        const int col = tid & 7;
        for (int tt = t + (tid >> 3); tt < n; tt += 32)
          __builtin_nontemporal_store(lds_h8[tt & 1][col],
                                      &hsout[(size_t)tt * HDIM + w * 8 + col]);
        if (wave == 0 && lane < 8) {
          float hlast = ((n - 1) & 1) ? hp1 : hp0;  // h(n-1)
          float clast = ((n - 1) & 1) ? cp1 : cp0;  // c(n-1)
          cstate = clast;
          u64 pub = (u64)(u32)(sbase + n) | ((u64)__float_as_uint(hlast) << 32);
          __hip_atomic_store(&a.hq[(size_t)((sbase + n) & 1) * HDIM + w * 8 + lane], pub,
                             __ATOMIC_RELAXED, __HIP_MEMORY_SCOPE_AGENT);
        }
        __syncthreads();
        fin = true;
        continue;
      }

      float acc0 = 0.f, acc1 = 0.f, acc2 = 0.f, acc3 = 0.f;
      const float4* lh4 = (const float4*)lds_h + chunk * 8;
#pragma unroll
      for (int i = 0; i < 8; ++i) {
        float4 h4 = lh4[(i + chunk) & 7];
        acc0 += wreg[0][i].x * h4.x + wreg[0][i].y * h4.y + wreg[0][i].z * h4.z + wreg[0][i].w * h4.w;
        acc1 += wreg[1][i].x * h4.x + wreg[1][i].y * h4.y + wreg[1][i].z * h4.z + wreg[1][i].w * h4.w;
        acc2 += wreg[2][i].x * h4.x + wreg[2][i].y * h4.y + wreg[2][i].z * h4.z + wreg[2][i].w * h4.w;
        acc3 += wreg[3][i].x * h4.x + wreg[3][i].y * h4.y + wreg[3][i].z * h4.z + wreg[3][i].w * h4.w;
      }
      {
        float4 p; p.x = acc0; p.y = acc1; p.z = acc2; p.w = acc3;
        *(float4*)&lds_part[chunk * 36 + rowgrp * 4] = p;
      }
      __syncthreads();  // B2

      if (wave == 0) {
        float sum = 0.f;
        if (lane < 32) {
#pragma unroll
          for (int cc = 0; cc < 32; ++cc) sum += lds_part[cc * 36 + lane];
          sum += (t == tspecial) ? my_gf : my_gc;
        }
        const int j = lane & 7;
        float gi = __shfl(sum, j);
        float gf2 = __shfl(sum, 8 + j);
        float gg = __shfl(sum, 16 + j);
        float go = __shfl(sum, 24 + j);
        if (lane < 8) {
          float iv = 1.f / (1.f + expf(-gi));
          float fv = 1.f / (1.f + expf(-gf2));
          float gv = tanhf(gg);
          float ov = 1.f / (1.f + expf(-go));
          float cnew = fv * cstate + iv * gv;
          float hn = ov * tanhf(cnew);
          float h2 = (t & 1) ? hp1 : hp0;   // h(t-2)
          float c2v = (t & 1) ? cp1 : cp0;  // c(t-2)
          int stab = (fabsf(hn - h2) <= CONV_TOL) &&
                     (fabsf(cnew - c2v) <= CONV_TOL) &&
                     (t > tspecial + 2) && (t >= 32);
          if (t & 1) { hp1 = hn; cp1 = cnew; } else { hp0 = hn; cp0 = cnew; }
          cstate = cnew;
          lds_h8[t & 1][j] = hn;
          __builtin_nontemporal_store(hn, &hsout[(size_t)t * HDIM + w * 8 + j]);
          u32 tagw = (u32)(s + 1) | ((u32)stab << 31);
          u64 pub = (u64)tagw | ((u64)__float_as_uint(hn) << 32);
          __hip_atomic_store(&a.hq[(size_t)((s + 1) & 1) * HDIM + w * 8 + j], pub,
                             __ATOMIC_RELAXED, __HIP_MEMORY_SCOPE_AGENT);
        }
      }
    }
  }
}

// ---------------- lin1_w transpose: L1T[k][j] = lin1_w[j][k] ----------------
__global__ void transpose_kernel(const float* __restrict__ A, float* __restrict__ AT) {
  __shared__ float tile[32][33];
  int j0 = blockIdx.y * 32, k0 = blockIdx.x * 32;
  int tx = threadIdx.x & 31, ty = threadIdx.x >> 5;  // ty 0..7
  for (int r = ty; r < 32; r += 8) tile[r][tx] = A[(size_t)(j0 + r) * HDIM + k0 + tx];
  __syncthreads();
  for (int r = ty; r < 32; r += 8) AT[(size_t)(k0 + r) * HDIM + j0 + tx] = tile[tx][r];
}

// ---------------- beta via tiled GEMM with register-double-buffered K-panels ----------------
// Tile: 128 t x 64 j, K-panels of 32. Grid (n/128, HDIM/64). Each thread: 8t x 4j micro-tile.
__global__ __launch_bounds__(256) void beta_gemm_kernel(
    const float* __restrict__ hsl, const float* __restrict__ hsr,
    const float* __restrict__ L1T, const float* __restrict__ b1,
    const float* __restrict__ u, float* __restrict__ beta) {
  __shared__ float As[32][128];
  __shared__ float Bs[32][64];
  const int tid = threadIdx.x;
  const int t0 = blockIdx.x * 128;
  const int j0 = blockIdx.y * 64;
  const int tm = tid >> 4;       // 0..15 -> rows t0 + tm*8 .. +7
  const int tj = tid & 15;       // 0..15 -> cols j0 + tj*4 .. +3
  const int sr = tid >> 1;       // A-staging row 0..127
  const int sc = (tid & 1) * 4;  // A-staging float4 col base

  float acc[8][4] = {};
  const float4 uv = *(const float4*)(u + j0 + tj * 4);
  const float4 bv = *(const float4*)(b1 + j0 + tj * 4);

  const float4* l4base = (const float4*)(hsl + (size_t)(t0 + sr) * HDIM);
  const float4* r4base = (const float4*)(hsr + (size_t)(t0 + sr) * HDIM);
  const int bkk0 = (tid + 0) >> 4, bjb0 = (tid + 0) & 15;
  const int bkk1 = (tid + 256) >> 4, bjb1 = (tid + 256) & 15;

  float4 ra[4], rb[4], rc0, rc1;
  {  // prologue: panel 0 into registers
#pragma unroll
    for (int i = 0; i < 4; ++i) { ra[i] = l4base[sc + i]; rb[i] = r4base[sc + i]; }
    rc0 = *(const float4*)(L1T + (size_t)bkk0 * HDIM + j0 + bjb0 * 4);
    rc1 = *(const float4*)(L1T + (size_t)bkk1 * HDIM + j0 + bjb1 * 4);
  }

  for (int k0 = 0; k0 < HDIM; k0 += 32) {
    {  // commit registers to LDS
#pragma unroll
      for (int i = 0; i < 4; ++i) {
        As[(sc + i) * 4 + 0][sr] = ra[i].x * rb[i].x;
        As[(sc + i) * 4 + 1][sr] = ra[i].y * rb[i].y;
        As[(sc + i) * 4 + 2][sr] = ra[i].z * rb[i].z;
        As[(sc + i) * 4 + 3][sr] = ra[i].w * rb[i].w;
      }
      *(float4*)&Bs[bkk0][bjb0 * 4] = rc0;
      *(float4*)&Bs[bkk1][bjb1 * 4] = rc1;
    }
    __syncthreads();
    if (k0 + 32 < HDIM) {  // prefetch next panel; vmcnt stays outstanding over compute
      const int kn = (k0 + 32) / 4;
#pragma unroll
      for (int i = 0; i < 4; ++i) { ra[i] = l4base[kn + sc + i]; rb[i] = r4base[kn + sc + i]; }
      rc0 = *(const float4*)(L1T + (size_t)(k0 + 32 + bkk0) * HDIM + j0 + bjb0 * 4);
      rc1 = *(const float4*)(L1T + (size_t)(k0 + 32 + bkk1) * HDIM + j0 + bjb1 * 4);
    }
#pragma unroll
    for (int kk = 0; kk < 32; ++kk) {
      float4 a0 = *(float4*)&As[kk][tm * 8];
      float4 a1 = *(float4*)&As[kk][tm * 8 + 4];
      float4 b = *(float4*)&Bs[kk][tj * 4];
      float ar[8] = {a0.x, a0.y, a0.z, a0.w, a1.x, a1.y, a1.z, a1.w};
      float bc[4] = {b.x, b.y, b.z, b.w};
#pragma unroll
      for (int r = 0; r < 8; ++r)
#pragma unroll
        for (int c = 0; c < 4; ++c) acc[r][c] += ar[r] * bc[c];
    }
    __syncthreads();
  }
  // epilogue: pb[r] = sum_c u[j]*tanh(acc + b1[j]); reduce over the 16 tj lanes; atomicAdd
  float ures[4] = {uv.x, uv.y, uv.z, uv.w};
  float bres[4] = {bv.x, bv.y, bv.z, bv.w};
#pragma unroll
  for (int r = 0; r < 8; ++r) {
    float pb = ures[0] * tanhf(acc[r][0] + bres[0]) + ures[1] * tanhf(acc[r][1] + bres[1]) +
               ures[2] * tanhf(acc[r][2] + bres[2]) + ures[3] * tanhf(acc[r][3] + bres[3]);
#pragma unroll
    for (int off = 1; off < 16; off <<= 1) pb += __shfl_xor(pb, off);
    if (tj == 0) atomicAdd(&beta[t0 + tm * 8 + r], pb);
  }
}

// ---------------- svec with fused softmax: s[h] += sum_t softmax(beta)[t]*O[t][h] ----------------
__global__ __launch_bounds__(256) void svec_kernel(const float* __restrict__ beta,
                                                   const float* __restrict__ hsl,
                                                   const float* __restrict__ hsr,
                                                   float* __restrict__ svec, int n) {
  __shared__ float sm[8];
  __shared__ float wts[256];
  __shared__ float red[4][64];
  const int tid = threadIdx.x, lane = tid & 63, wv = tid >> 6;
  // softmax stats over the full beta (small; L2-broadcast across blocks)
  float m = -3.4e38f;
  for (int i = tid; i < n; i += 256) m = fmaxf(m, beta[i]);
  for (int off = 32; off; off >>= 1) m = fmaxf(m, __shfl_xor(m, off));
  if (lane == 0) sm[wv] = m;
  __syncthreads();
  const float M = fmaxf(fmaxf(sm[0], sm[1]), fmaxf(sm[2], sm[3]));
  float z = 0.f;
  for (int i = tid; i < n; i += 256) z += expf(beta[i] - M);
  for (int off = 32; off; off >>= 1) z += __shfl_xor(z, off);
  if (lane == 0) sm[4 + wv] = z;
  __syncthreads();
  const float invZ = 1.f / (sm[4] + sm[5] + sm[6] + sm[7]);
  const int tlen = n / gridDim.y;   // 256 for n=2048, gridDim.y=8
  const int tbeg = blockIdx.y * tlen;
  for (int i = tid; i < tlen; i += 256) wts[i] = expf(beta[tbeg + i] - M) * invZ;
  __syncthreads();
  const int h = blockIdx.x * 64 + lane;
  const int ts = wv;
  float s = 0.f;
  for (int t = ts; t < tlen; t += 4)
    s += wts[t] * hsl[(size_t)(tbeg + t) * HDIM + h] * hsr[(size_t)(tbeg + t) * HDIM + h];
  red[ts][lane] = s;
  __syncthreads();
  if (tid < 64) {
    float tot = red[0][tid] + red[1][tid] + red[2][tid] + red[3][tid];
    atomicAdd(&svec[blockIdx.x * 64 + tid], tot);
  }
}

// ---------------- out[r] = lin2_w[r] . s + lin2_b[r] ----------------
__global__ void final_kernel(const float* __restrict__ svec, const float* __restrict__ l2w,
                             const float* __restrict__ l2b, float* __restrict__ out) {
  int r = threadIdx.x >> 6, lane = threadIdx.x & 63;
  float s = 0.f;
  for (int k = lane; k < HDIM; k += 64) s += l2w[(size_t)r * HDIM + k] * svec[k];
  for (int off = 32; off; off >>= 1) s += __shfl_xor(s, off);
  if (lane == 0) out[r] = s + l2b[r];
}

extern "C" void kernel_launch(void* const* d_in, const int* in_sizes, int n_in,
                              void* d_out, int out_size, void* d_ws, size_t ws_size,
                              hipStream_t stream) {
  const int* x = (const int*)d_in[0];
  const int* tstart = (const int*)d_in[1];
  const int* tend = (const int*)d_in[2];
  const float* emb = (const float*)d_in[3];
  const float* wih_l = (const float*)d_in[4];
  const float* whh_l = (const float*)d_in[5];
  const float* bih_l = (const float*)d_in[6];
  const float* bhh_l = (const float*)d_in[7];
  const float* wih_r = (const float*)d_in[8];
  const float* whh_r = (const float*)d_in[9];
  const float* bih_r = (const float*)d_in[10];
  const float* bhh_r = (const float*)d_in[11];
  const float* l1w = (const float*)d_in[12];
  const float* l1b = (const float*)d_in[13];
  const float* u = (const float*)d_in[14];
  const float* l2w = (const float*)d_in[15];
  const float* l2b = (const float*)d_in[16];
  const int n = in_sizes[0];  // 2048
  (void)n_in; (void)out_size; (void)ws_size;

  float* ws = (float*)d_ws;
  float* target = ws;                     // 1024
  float* seqfl = ws + 1024;               // 1024
  float* seqfr = ws + 2048;               // 1024
  float* glc = ws + 3072;                 // 4096
  float* glf = glc + 4096;                // 4096
  float* grc = glf + 4096;                // 4096
  float* grf = grc + 4096;                // 4096
  u64* hq = (u64*)(grf + 4096);           // 2*1024 u64 (8B aligned)
  float* hsl = (float*)(hq + 2 * HDIM);   // n*1024
  float* hsr = hsl + (size_t)n * HDIM;    // n*1024
  float* L1T = hsr + (size_t)n * HDIM;    // 1024*1024
  float* beta = L1T + (size_t)HDIM * HDIM;  // n
  float* svec = beta + n;                 // 1024

  setup_kernel<<<1, 1024, 0, stream>>>(x, tstart, tend, emb, target, seqfl, seqfr, hq,
                                       beta, svec, n);
  gateconst_kernel<<<dim3(1024, 2), 256, 0, stream>>>(wih_l, bih_l, bhh_l, wih_r, bih_r, bhh_r,
                                                      target, seqfl, seqfr, glc, glf, grc, grf);
  RecArgs ra;
  ra.whh_l = whh_l; ra.whh_r = whh_r;
  ra.glc = glc; ra.glf = glf; ra.grc = grc; ra.grf = grf;
  ra.hq = hq; ra.hsl = hsl; ra.hsr = hsr;
  ra.pstart = tstart; ra.pend = tend; ra.n = n;
  void* kargs[] = {(void*)&ra};
  hipLaunchCooperativeKernel((const void*)rec_kernel, dim3(NWG), dim3(TPB), kargs, 0, stream);

  transpose_kernel<<<dim3(32, 32), 256, 0, stream>>>(l1w, L1T);
  beta_gemm_kernel<<<dim3(n / 128, HDIM / 64), 256, 0, stream>>>(hsl, hsr, L1T, l1b, u, beta);
  svec_kernel<<<dim3(16, 8), 256, 0, stream>>>(beta, hsl, hsr, svec, n);
  final_kernel<<<1, 192, 0, stream>>>(svec, l2w, l2b, (float*)d_out);
}